// Round 3
// baseline (2267.410 us; speedup 1.0000x reference)
//
#include <hip/hip_runtime.h>
#include <hip/hip_bf16.h>

typedef unsigned short u16;

#define N_NODES 50000
#define N_EDGES 400000
#define ET      450000   // edges + self loops
#define F_IN    128
#define C1      256      // H*HID
#define HID     64
#define OUTC    64
#define SLOPE   0.2f

__device__ __forceinline__ float bf2f(u16 v) {
    return __uint_as_float(((unsigned)v) << 16);
}
__device__ __forceinline__ float bflo(unsigned u) { return __uint_as_float(u << 16); }
__device__ __forceinline__ float bfhi(unsigned u) { return __uint_as_float(u & 0xffff0000u); }
__device__ __forceinline__ u16 f2bf(float f) {   // round-to-nearest-even
    unsigned u = __float_as_uint(f);
    return (u16)((u + 0x7fffu + ((u >> 16) & 1u)) >> 16);
}
__device__ __forceinline__ float sanitize(float f) {  // non-finite -> 0
    unsigned u = __float_as_uint(f);
    return ((u & 0x7f800000u) == 0x7f800000u) ? 0.f : f;
}
// monotone float<->uint flip for atomicMax on floats
__device__ __forceinline__ unsigned flipf(float f) {
    unsigned u = __float_as_uint(f);
    return (u & 0x80000000u) ? ~u : (u | 0x80000000u);
}
__device__ __forceinline__ float unflipf(unsigned u) {
    unsigned v = (u & 0x80000000u) ? (u & 0x7fffffffu) : ~u;
    return __uint_as_float(v);
}

// ---------------- dtype detector ----------------
// Reads first 256 32-bit words of x. If data is f32, the low 16 bits of each
// word are mantissa bits -> interpreting them as bf16 gives a uniform-random
// exponent field -> ~50% "extreme". If data is bf16 pairs, the low half is a
// real N(0,1) bf16 sample -> extreme count ~0. Threshold 32.
__global__ __launch_bounds__(256) void detect_kernel(const unsigned* __restrict__ xw,
                                                     int* __restrict__ cnt)
{
    unsigned w = xw[threadIdx.x];
    unsigned aexp = (w >> 7) & 0xFFu;   // exponent field of low-half bf16
    if (aexp >= 170u || aexp <= 40u) atomicAdd(cnt, 1);
}

// convert one param array to bf16 (copy if already bf16)
__global__ __launch_bounds__(256) void convert_kernel(const void* __restrict__ src,
                                                      u16* __restrict__ dst, int n,
                                                      const int* __restrict__ cnt)
{
    int t = blockIdx.x * 256 + threadIdx.x;
    if (t >= n) return;
    bool f32m = (*cnt >= 32);
    dst[t] = f32m ? f2bf(((const float*)src)[t]) : ((const u16*)src)[t];
}

// ---------------- GEMM: Y[r, ct*MT + c] = X[r,:] @ W[:, ct*MT + c] + B ----------
// block = 256 threads; each thread computes 4 consecutive output cols of one row.
// W/Bv are always bf16 (pre-converted). X may be f32 (dual=true + flag) or bf16.
template<int K, int M, int MT>
__global__ __launch_bounds__(256) void linear_kernel(
    const u16* __restrict__ X, const u16* __restrict__ W,
    const u16* __restrict__ Bv, u16* __restrict__ Y, int nrows,
    const int* __restrict__ cnt, int dual)
{
    constexpr int CPT = 4;
    constexpr int TPR = MT / CPT;      // threads per row
    constexpr int RPB = 256 / TPR;     // rows per block
    __shared__ __align__(16) u16 sW[K * MT];
    __shared__ __align__(16) u16 sX[RPB * K];

    const bool f32m = dual && (*cnt >= 32);
    const float* X32 = (const float*)X;

    const int ct = blockIdx.y;
    // stage W column-slice (bf16 always)
    for (int i = threadIdx.x * 8; i < K * MT; i += 256 * 8) {
        int k = i / MT, c = i % MT;
        *(uint4*)&sW[i] = *(const uint4*)&W[(size_t)k * M + ct * MT + c];
    }
    // stage X rows
    const int row0 = blockIdx.x * RPB;
    for (int i = threadIdx.x * 8; i < RPB * K; i += 256 * 8) {
        int r = i / K, k = i % K;
        int gr = row0 + r;
        size_t xbase = (size_t)gr * K + k;
        if (f32m) {
            float4 v0 = make_float4(0.f, 0.f, 0.f, 0.f), v1 = v0;
            if (gr < nrows) {
                v0 = *(const float4*)&X32[xbase];
                v1 = *(const float4*)&X32[xbase + 4];
            }
            ushort4 p0, p1;
            p0.x = f2bf(v0.x); p0.y = f2bf(v0.y); p0.z = f2bf(v0.z); p0.w = f2bf(v0.w);
            p1.x = f2bf(v1.x); p1.y = f2bf(v1.y); p1.z = f2bf(v1.z); p1.w = f2bf(v1.w);
            *(ushort4*)&sX[i] = p0;
            *(ushort4*)&sX[i + 4] = p1;
        } else {
            uint4 v = {0u, 0u, 0u, 0u};
            if (gr < nrows) v = *(const uint4*)&X[xbase];
            *(uint4*)&sX[i] = v;
        }
    }
    __syncthreads();

    const int rl = threadIdx.x / TPR;
    const int c0 = (threadIdx.x % TPR) * CPT;
    const int row = row0 + rl;
    if (row >= nrows) return;

    float a0 = 0.f, a1 = 0.f, a2 = 0.f, a3 = 0.f;
    const u16* xp = &sX[rl * K];
    #pragma unroll 8
    for (int k = 0; k < K; k += 2) {
        unsigned xu = *(const unsigned*)&xp[k];
        float x0 = bflo(xu), x1 = bfhi(xu);
        uint2 w0 = *(const uint2*)&sW[k * MT + c0];
        uint2 w1 = *(const uint2*)&sW[(k + 1) * MT + c0];
        a0 += x0 * bflo(w0.x); a1 += x0 * bfhi(w0.x);
        a2 += x0 * bflo(w0.y); a3 += x0 * bfhi(w0.y);
        a0 += x1 * bflo(w1.x); a1 += x1 * bfhi(w1.x);
        a2 += x1 * bflo(w1.y); a3 += x1 * bfhi(w1.y);
    }
    a0 = sanitize(a0); a1 = sanitize(a1); a2 = sanitize(a2); a3 = sanitize(a3);
    const int cg = ct * MT + c0;
    ushort4 o;
    o.x = f2bf(a0 + bf2f(Bv[cg + 0]));
    o.y = f2bf(a1 + bf2f(Bv[cg + 1]));
    o.z = f2bf(a2 + bf2f(Bv[cg + 2]));
    o.w = f2bf(a3 + bf2f(Bv[cg + 3]));
    *(ushort4*)&Y[(size_t)row * M + cg] = o;
}

// ---------------- layer 1 edge kernels (4 heads x 64 ch) ----------------
// one wave per edge; lane l covers channels [4l, 4l+4), head = l>>4
__global__ __launch_bounds__(256) void scores1_kernel(
    const u16* __restrict__ xl, const u16* __restrict__ xr,
    const int* __restrict__ ei, const u16* __restrict__ att,
    float* __restrict__ alpha, unsigned* __restrict__ mx)
{
    int gid = blockIdx.x * 256 + threadIdx.x;
    int e = gid >> 6, l = gid & 63;
    int s, d;
    if (e < N_EDGES) { s = ei[e]; d = ei[N_EDGES + e]; } else { s = d = e - N_EDGES; }
    ushort4 av = *(const ushort4*)&att[l * 4];
    ushort4 xs = *(const ushort4*)&xl[(size_t)s * C1 + l * 4];
    ushort4 xt = *(const ushort4*)&xr[(size_t)d * C1 + l * 4];
    float p = 0.f, m;
    m = bf2f(xs.x) + bf2f(xt.x); m = m > 0.f ? m : SLOPE * m; p += m * bf2f(av.x);
    m = bf2f(xs.y) + bf2f(xt.y); m = m > 0.f ? m : SLOPE * m; p += m * bf2f(av.y);
    m = bf2f(xs.z) + bf2f(xt.z); m = m > 0.f ? m : SLOPE * m; p += m * bf2f(av.z);
    m = bf2f(xs.w) + bf2f(xt.w); m = m > 0.f ? m : SLOPE * m; p += m * bf2f(av.w);
    p += __shfl_xor(p, 1);
    p += __shfl_xor(p, 2);
    p += __shfl_xor(p, 4);
    p += __shfl_xor(p, 8);
    if ((l & 15) == 0) {
        int h = l >> 4;
        alpha[(size_t)e * 4 + h] = p;
        atomicMax(&mx[(size_t)d * 4 + h], flipf(p));
    }
}

__global__ __launch_bounds__(256) void expsum1_kernel(
    const int* __restrict__ ei, float* __restrict__ alpha,
    const unsigned* __restrict__ mx, float* __restrict__ denom)
{
    int t = blockIdx.x * 256 + threadIdx.x;
    if (t >= ET * 4) return;
    int e = t >> 2, h = t & 3;
    int d = (e < N_EDGES) ? ei[N_EDGES + e] : e - N_EDGES;
    float ex = expf(fminf(alpha[t] - unflipf(mx[d * 4 + h]), 0.f));
    alpha[t] = ex;
    atomicAdd(&denom[(size_t)d * 4 + h], ex);
}

__global__ __launch_bounds__(256) void agg1_kernel(
    const u16* __restrict__ xl, const int* __restrict__ ei,
    const float* __restrict__ alpha, const float* __restrict__ denom,
    float* __restrict__ out)
{
    int gid = blockIdx.x * 256 + threadIdx.x;
    int e = gid >> 6, l = gid & 63;
    int s, d;
    if (e < N_EDGES) { s = ei[e]; d = ei[N_EDGES + e]; } else { s = d = e - N_EDGES; }
    int h = l >> 4;
    float w = alpha[(size_t)e * 4 + h] / fmaxf(denom[(size_t)d * 4 + h], 1e-38f);
    ushort4 xs = *(const ushort4*)&xl[(size_t)s * C1 + l * 4];
    float* o = &out[(size_t)d * C1 + l * 4];
    atomicAdd(o + 0, w * bf2f(xs.x));
    atomicAdd(o + 1, w * bf2f(xs.y));
    atomicAdd(o + 2, w * bf2f(xs.z));
    atomicAdd(o + 3, w * bf2f(xs.w));
}

__global__ __launch_bounds__(256) void elu_bias_kernel(
    const float* __restrict__ acc, const u16* __restrict__ bias, u16* __restrict__ h)
{
    int t = blockIdx.x * 256 + threadIdx.x;
    float v = acc[t] + bf2f(bias[t & (C1 - 1)]);
    float o = v > 0.f ? v : expf(fminf(v, 0.f)) - 1.f;
    h[t] = f2bf(o);
}

// ---------------- layer 2 edge kernels (1 head x 64 ch) ----------------
__global__ __launch_bounds__(256) void scores2_kernel(
    const u16* __restrict__ xl, const u16* __restrict__ xr,
    const int* __restrict__ ei, const u16* __restrict__ att,
    float* __restrict__ alpha, unsigned* __restrict__ mx)
{
    int gid = blockIdx.x * 256 + threadIdx.x;
    int e = gid >> 6, l = gid & 63;
    int s, d;
    if (e < N_EDGES) { s = ei[e]; d = ei[N_EDGES + e]; } else { s = d = e - N_EDGES; }
    float m = bf2f(xl[(size_t)s * OUTC + l]) + bf2f(xr[(size_t)d * OUTC + l]);
    m = m > 0.f ? m : SLOPE * m;
    float p = m * bf2f(att[l]);
    p += __shfl_xor(p, 32);
    p += __shfl_xor(p, 16);
    p += __shfl_xor(p, 8);
    p += __shfl_xor(p, 4);
    p += __shfl_xor(p, 2);
    p += __shfl_xor(p, 1);
    if (l == 0) {
        alpha[e] = p;
        atomicMax(&mx[d], flipf(p));
    }
}

__global__ __launch_bounds__(256) void expsum2_kernel(
    const int* __restrict__ ei, float* __restrict__ alpha,
    const unsigned* __restrict__ mx, float* __restrict__ denom)
{
    int e = blockIdx.x * 256 + threadIdx.x;
    if (e >= ET) return;
    int d = (e < N_EDGES) ? ei[N_EDGES + e] : e - N_EDGES;
    float ex = expf(fminf(alpha[e] - unflipf(mx[d]), 0.f));
    alpha[e] = ex;
    atomicAdd(&denom[d], ex);
}

__global__ __launch_bounds__(256) void agg2_kernel(
    const u16* __restrict__ xl, const int* __restrict__ ei,
    const float* __restrict__ alpha, const float* __restrict__ denom,
    float* __restrict__ out)
{
    int gid = blockIdx.x * 256 + threadIdx.x;
    int e = gid >> 6, l = gid & 63;
    int s, d;
    if (e < N_EDGES) { s = ei[e]; d = ei[N_EDGES + e]; } else { s = d = e - N_EDGES; }
    float w = alpha[e] / fmaxf(denom[d], 1e-38f);
    atomicAdd(&out[(size_t)d * OUTC + l], w * bf2f(xl[(size_t)s * OUTC + l]));
}

__global__ __launch_bounds__(256) void final_kernel(
    const float* __restrict__ acc, const u16* __restrict__ bias,
    void* __restrict__ outp, const int* __restrict__ cnt)
{
    int t = blockIdx.x * 256 + threadIdx.x;
    float v = acc[t] + bf2f(bias[t & (OUTC - 1)]);
    if (*cnt >= 32) ((float*)outp)[t] = v;
    else            ((u16*)outp)[t]   = f2bf(v);
}

extern "C" void kernel_launch(void* const* d_in, const int* in_sizes, int n_in,
                              void* d_out, int out_size, void* d_ws, size_t ws_size,
                              hipStream_t stream)
{
    const void* x     = d_in[0];
    const int*  ei    = (const int*)d_in[1];

    char* ws = (char*)d_ws;
    // layout (bytes), peak ~85.8 MB:
    u16*      xl1    = (u16*)     (ws + 0);            // [0, 25.6M)
    u16*      xr1    = (u16*)     (ws + 25600000);     // dead after scores1
    float*    out1   = (float*)   (ws + 25600000);     // overlays xr1 after scores1
    float*    alpha1 = (float*)   (ws + 76800000);
    unsigned* mx1    = (unsigned*)(ws + 84000000);
    float*    denom1 = (float*)   (ws + 84800000);
    int*      cnt    = (int*)     (ws + 85600000);
    u16*      prm    = (u16*)     (ws + 85600064);     // converted bf16 params
    u16*      hbuf   = (u16*)     (ws + 0);            // reuse xl1 (dead after agg1)
    u16*      xl2    = (u16*)     (ws + 25600000);     // over dead out1
    u16*      xr2    = (u16*)     (ws + 32000000);
    float*    alpha2 = (float*)   (ws + 38400000);
    unsigned* mx2    = (unsigned*)(ws + 40200000);
    float*    denom2 = (float*)   (ws + 40400000);
    float*    out2   = (float*)   (ws + 40600000);

    // converted-param element offsets
    u16* Wl1   = prm + 0;      // 32768
    u16* bl1   = prm + 32768;  // 256
    u16* Wr1   = prm + 33024;  // 32768
    u16* br1   = prm + 65792;  // 256
    u16* att1  = prm + 66048;  // 256
    u16* bias1 = prm + 66304;  // 256
    u16* Wl2   = prm + 66560;  // 16384
    u16* bl2   = prm + 82944;  // 64
    u16* Wr2   = prm + 83008;  // 16384
    u16* br2   = prm + 99392;  // 64
    u16* att2  = prm + 99456;  // 64
    u16* bias2 = prm + 99520;  // 64

    // dtype detection
    hipMemsetAsync(cnt, 0, 4, stream);
    detect_kernel<<<1, 256, 0, stream>>>((const unsigned*)x, cnt);

    // convert params to bf16 (or copy if already bf16)
    const int psz[12] = {32768, 256, 32768, 256, 256, 256, 16384, 64, 16384, 64, 64, 64};
    u16* pdst[12] = {Wl1, bl1, Wr1, br1, att1, bias1, Wl2, bl2, Wr2, br2, att2, bias2};
    for (int i = 0; i < 12; ++i)
        convert_kernel<<<(psz[i] + 255) / 256, 256, 0, stream>>>(d_in[2 + i], pdst[i], psz[i], cnt);

    // flip-encoded max init (0u beats nothing; every node has a self-loop)
    hipMemsetAsync(mx1, 0, 1600000, stream);   // mx1 + denom1 contiguous

    // layer 1 linear (X may be f32)
    {
        dim3 g(N_NODES / 8, 2);   // MT=128 -> RPB=8, two col-tiles
        linear_kernel<128, 256, 128><<<g, 256, 0, stream>>>((const u16*)x, Wl1, bl1, xl1, N_NODES, cnt, 1);
        linear_kernel<128, 256, 128><<<g, 256, 0, stream>>>((const u16*)x, Wr1, br1, xr1, N_NODES, cnt, 1);
    }
    const int edge_wave_blocks = ET * 64 / 256;  // 112500, exact
    scores1_kernel<<<edge_wave_blocks, 256, 0, stream>>>(xl1, xr1, ei, att1, alpha1, mx1);
    hipMemsetAsync(out1, 0, 51200000, stream);   // xr1 dead now; out1 overlays it
    expsum1_kernel<<<(ET * 4 + 255) / 256, 256, 0, stream>>>(ei, alpha1, mx1, denom1);
    agg1_kernel<<<edge_wave_blocks, 256, 0, stream>>>(xl1, ei, alpha1, denom1, out1);
    elu_bias_kernel<<<(N_NODES * C1) / 256, 256, 0, stream>>>(out1, bias1, hbuf);

    // layer 2 linear (input hbuf is internal bf16)
    {
        dim3 g(N_NODES / 16, 1);  // MT=64 -> RPB=16
        linear_kernel<256, 64, 64><<<g, 256, 0, stream>>>(hbuf, Wl2, bl2, xl2, N_NODES, cnt, 0);
        linear_kernel<256, 64, 64><<<g, 256, 0, stream>>>(hbuf, Wr2, br2, xr2, N_NODES, cnt, 0);
    }
    hipMemsetAsync(mx2, 0, 400000, stream);      // mx2 + denom2 contiguous
    hipMemsetAsync(out2, 0, 12800000, stream);
    scores2_kernel<<<edge_wave_blocks, 256, 0, stream>>>(xl2, xr2, ei, att2, alpha2, mx2);
    expsum2_kernel<<<(ET + 255) / 256, 256, 0, stream>>>(ei, alpha2, mx2, denom2);
    agg2_kernel<<<edge_wave_blocks, 256, 0, stream>>>(xl2, ei, alpha2, denom2, out2);
    final_kernel<<<(N_NODES * OUTC) / 256, 256, 0, stream>>>(out2, bias2, d_out, cnt);
}

// Round 4
// 702.538 us; speedup vs baseline: 3.2275x; 3.2275x over previous
//
#include <hip/hip_runtime.h>
#include <hip/hip_bf16.h>

typedef unsigned short u16;

#define N_NODES 50000
#define N_EDGES 400000
#define ET      450000   // edges + self loops
#define F_IN    128
#define C1      256      // H*HID
#define HID     64
#define OUTC    64
#define SLOPE   0.2f

__device__ __forceinline__ float bf2f(u16 v) {
    return __uint_as_float(((unsigned)v) << 16);
}
__device__ __forceinline__ float bflo(unsigned u) { return __uint_as_float(u << 16); }
__device__ __forceinline__ float bfhi(unsigned u) { return __uint_as_float(u & 0xffff0000u); }
__device__ __forceinline__ u16 f2bf(float f) {   // round-to-nearest-even
    unsigned u = __float_as_uint(f);
    return (u16)((u + 0x7fffu + ((u >> 16) & 1u)) >> 16);
}
__device__ __forceinline__ float sanitize(float f) {  // non-finite -> 0
    unsigned u = __float_as_uint(f);
    return ((u & 0x7f800000u) == 0x7f800000u) ? 0.f : f;
}

// ---------------- dtype detector (f32 vs bf16 input buffers) ----------------
__global__ __launch_bounds__(256) void detect_kernel(const unsigned* __restrict__ xw,
                                                     int* __restrict__ cnt)
{
    unsigned w = xw[threadIdx.x];
    unsigned aexp = (w >> 7) & 0xFFu;   // exponent field of low-half bf16
    if (aexp >= 170u || aexp <= 40u) atomicAdd(cnt, 1);
}

// convert one param array to bf16 (copy if already bf16)
__global__ __launch_bounds__(256) void convert_kernel(const void* __restrict__ src,
                                                      u16* __restrict__ dst, int n,
                                                      const int* __restrict__ cnt)
{
    int t = blockIdx.x * 256 + threadIdx.x;
    if (t >= n) return;
    bool f32m = (*cnt >= 32);
    dst[t] = f32m ? f2bf(((const float*)src)[t]) : ((const u16*)src)[t];
}

// ---------------- CSR build (by dst) ----------------
__global__ __launch_bounds__(256) void hist_kernel(const int* __restrict__ ei,
                                                   int* __restrict__ hist)
{
    int t = blockIdx.x * 256 + threadIdx.x;
    if (t >= ET) return;
    int d = (t < N_EDGES) ? ei[N_EDGES + t] : t - N_EDGES;
    atomicAdd(&hist[d], 1);
}

__global__ __launch_bounds__(1024) void scan_kernel(const int* __restrict__ hist,
                                                    int* __restrict__ rowptr,
                                                    int* __restrict__ off)
{
    constexpr int SEG = 49;  // 1024*49 >= 50000
    __shared__ int ssum[1024];
    int t = threadIdx.x;
    int base = t * SEG;
    int s = 0;
    for (int i = 0; i < SEG; ++i) {
        int idx = base + i;
        if (idx < N_NODES) s += hist[idx];
    }
    ssum[t] = s;
    __syncthreads();
    for (int ofs = 1; ofs < 1024; ofs <<= 1) {
        int v = (t >= ofs) ? ssum[t - ofs] : 0;
        __syncthreads();
        ssum[t] += v;
        __syncthreads();
    }
    int run = ssum[t] - s;   // exclusive prefix of this segment
    for (int i = 0; i < SEG; ++i) {
        int idx = base + i;
        if (idx < N_NODES) {
            rowptr[idx] = run;
            off[idx] = run;
            run += hist[idx];
        }
    }
}

__global__ __launch_bounds__(256) void scatter_kernel(const int* __restrict__ ei,
                                                      int* __restrict__ off,
                                                      int* __restrict__ src_csr)
{
    int t = blockIdx.x * 256 + threadIdx.x;
    if (t >= ET) return;
    int s, d;
    if (t < N_EDGES) { s = ei[t]; d = ei[N_EDGES + t]; } else { s = d = t - N_EDGES; }
    int pos = atomicAdd(&off[d], 1);
    src_csr[pos] = s;
}

// ---------------- GEMM: Y[r, ct*MT + c] = X[r,:] @ W[:, ct*MT + c] + B ----------
template<int K, int M, int MT>
__global__ __launch_bounds__(256) void linear_kernel(
    const u16* __restrict__ X, const u16* __restrict__ W,
    const u16* __restrict__ Bv, u16* __restrict__ Y, int nrows,
    const int* __restrict__ cnt, int dual)
{
    constexpr int CPT = 4;
    constexpr int TPR = MT / CPT;
    constexpr int RPB = 256 / TPR;
    __shared__ __align__(16) u16 sW[K * MT];
    __shared__ __align__(16) u16 sX[RPB * K];

    const bool f32m = dual && (*cnt >= 32);
    const float* X32 = (const float*)X;

    const int ct = blockIdx.y;
    for (int i = threadIdx.x * 8; i < K * MT; i += 256 * 8) {
        int k = i / MT, c = i % MT;
        *(uint4*)&sW[i] = *(const uint4*)&W[(size_t)k * M + ct * MT + c];
    }
    const int row0 = blockIdx.x * RPB;
    for (int i = threadIdx.x * 8; i < RPB * K; i += 256 * 8) {
        int r = i / K, k = i % K;
        int gr = row0 + r;
        size_t xbase = (size_t)gr * K + k;
        if (f32m) {
            float4 v0 = make_float4(0.f, 0.f, 0.f, 0.f), v1 = v0;
            if (gr < nrows) {
                v0 = *(const float4*)&X32[xbase];
                v1 = *(const float4*)&X32[xbase + 4];
            }
            ushort4 p0, p1;
            p0.x = f2bf(v0.x); p0.y = f2bf(v0.y); p0.z = f2bf(v0.z); p0.w = f2bf(v0.w);
            p1.x = f2bf(v1.x); p1.y = f2bf(v1.y); p1.z = f2bf(v1.z); p1.w = f2bf(v1.w);
            *(ushort4*)&sX[i] = p0;
            *(ushort4*)&sX[i + 4] = p1;
        } else {
            uint4 v = {0u, 0u, 0u, 0u};
            if (gr < nrows) v = *(const uint4*)&X[xbase];
            *(uint4*)&sX[i] = v;
        }
    }
    __syncthreads();

    const int rl = threadIdx.x / TPR;
    const int c0 = (threadIdx.x % TPR) * CPT;
    const int row = row0 + rl;
    if (row >= nrows) return;

    float a0 = 0.f, a1 = 0.f, a2 = 0.f, a3 = 0.f;
    const u16* xp = &sX[rl * K];
    #pragma unroll 8
    for (int k = 0; k < K; k += 2) {
        unsigned xu = *(const unsigned*)&xp[k];
        float x0 = bflo(xu), x1 = bfhi(xu);
        uint2 w0 = *(const uint2*)&sW[k * MT + c0];
        uint2 w1 = *(const uint2*)&sW[(k + 1) * MT + c0];
        a0 += x0 * bflo(w0.x); a1 += x0 * bfhi(w0.x);
        a2 += x0 * bflo(w0.y); a3 += x0 * bfhi(w0.y);
        a0 += x1 * bflo(w1.x); a1 += x1 * bfhi(w1.x);
        a2 += x1 * bflo(w1.y); a3 += x1 * bfhi(w1.y);
    }
    a0 = sanitize(a0); a1 = sanitize(a1); a2 = sanitize(a2); a3 = sanitize(a3);
    const int cg = ct * MT + c0;
    ushort4 o;
    o.x = f2bf(a0 + bf2f(Bv[cg + 0]));
    o.y = f2bf(a1 + bf2f(Bv[cg + 1]));
    o.z = f2bf(a2 + bf2f(Bv[cg + 2]));
    o.w = f2bf(a3 + bf2f(Bv[cg + 3]));
    *(ushort4*)&Y[(size_t)row * M + cg] = o;
}

// ---------------- layer 1 fused per-node GATv2 (4 heads x 64 ch) ----------------
// one wave per node; lane l: head h=l>>4, channels [4l, 4l+4)
// online softmax over the node's incoming edges; bias+ELU fused.
__global__ __launch_bounds__(256) void node1_kernel(
    const u16* __restrict__ xl, const u16* __restrict__ xr,
    const int* __restrict__ rowptr, const int* __restrict__ hist,
    const int* __restrict__ src_csr, const u16* __restrict__ att,
    const u16* __restrict__ bias, u16* __restrict__ hout)
{
    int gid = blockIdx.x * 256 + threadIdx.x;
    int d = gid >> 6, l = gid & 63;
    if (d >= N_NODES) return;
    const int start = rowptr[d];
    const int deg = hist[d];

    ushort4 av = *(const ushort4*)&att[l * 4];
    const float at0 = bf2f(av.x), at1 = bf2f(av.y), at2 = bf2f(av.z), at3 = bf2f(av.w);
    ushort4 xrv = *(const ushort4*)&xr[(size_t)d * C1 + l * 4];
    const float r0 = bf2f(xrv.x), r1 = bf2f(xrv.y), r2 = bf2f(xrv.z), r3 = bf2f(xrv.w);

    float m = -1e30f, la = 0.f;
    float a0 = 0.f, a1 = 0.f, a2 = 0.f, a3 = 0.f;
    for (int j = 0; j < deg; ++j) {
        int s = src_csr[start + j];
        ushort4 xv = *(const ushort4*)&xl[(size_t)s * C1 + l * 4];
        float x0 = bf2f(xv.x), x1 = bf2f(xv.y), x2 = bf2f(xv.z), x3 = bf2f(xv.w);
        float t, p = 0.f;
        t = x0 + r0; t = t > 0.f ? t : SLOPE * t; p += t * at0;
        t = x1 + r1; t = t > 0.f ? t : SLOPE * t; p += t * at1;
        t = x2 + r2; t = t > 0.f ? t : SLOPE * t; p += t * at2;
        t = x3 + r3; t = t > 0.f ? t : SLOPE * t; p += t * at3;
        p += __shfl_xor(p, 1);    // reduce within 16-lane head group
        p += __shfl_xor(p, 2);
        p += __shfl_xor(p, 4);
        p += __shfl_xor(p, 8);
        float mn = fmaxf(m, p);
        float sc = __expf(m - mn);
        float w  = __expf(p - mn);
        la = la * sc + w;
        a0 = a0 * sc + w * x0;
        a1 = a1 * sc + w * x1;
        a2 = a2 * sc + w * x2;
        a3 = a3 * sc + w * x3;
        m = mn;
    }
    const float inv = 1.f / la;   // deg >= 1 (self-loop) -> la >= 1
    const int c = l * 4;
    float v0 = a0 * inv + bf2f(bias[c + 0]);
    float v1 = a1 * inv + bf2f(bias[c + 1]);
    float v2 = a2 * inv + bf2f(bias[c + 2]);
    float v3 = a3 * inv + bf2f(bias[c + 3]);
    v0 = v0 > 0.f ? v0 : __expf(fminf(v0, 0.f)) - 1.f;
    v1 = v1 > 0.f ? v1 : __expf(fminf(v1, 0.f)) - 1.f;
    v2 = v2 > 0.f ? v2 : __expf(fminf(v2, 0.f)) - 1.f;
    v3 = v3 > 0.f ? v3 : __expf(fminf(v3, 0.f)) - 1.f;
    ushort4 o;
    o.x = f2bf(v0); o.y = f2bf(v1); o.z = f2bf(v2); o.w = f2bf(v3);
    *(ushort4*)&hout[(size_t)d * C1 + c] = o;
}

// ---------------- layer 2 fused per-node GATv2 (1 head x 64 ch) ----------------
__global__ __launch_bounds__(256) void node2_kernel(
    const u16* __restrict__ xl, const u16* __restrict__ xr,
    const int* __restrict__ rowptr, const int* __restrict__ hist,
    const int* __restrict__ src_csr, const u16* __restrict__ att,
    const u16* __restrict__ bias, void* __restrict__ outp,
    const int* __restrict__ cnt)
{
    int gid = blockIdx.x * 256 + threadIdx.x;
    int d = gid >> 6, l = gid & 63;
    if (d >= N_NODES) return;
    const int start = rowptr[d];
    const int deg = hist[d];

    const float at = bf2f(att[l]);
    const float r  = bf2f(xr[(size_t)d * OUTC + l]);

    float m = -1e30f, la = 0.f, a = 0.f;
    for (int j = 0; j < deg; ++j) {
        int s = src_csr[start + j];
        float x = bf2f(xl[(size_t)s * OUTC + l]);
        float t = x + r;
        t = t > 0.f ? t : SLOPE * t;
        float p = t * at;
        p += __shfl_xor(p, 1);
        p += __shfl_xor(p, 2);
        p += __shfl_xor(p, 4);
        p += __shfl_xor(p, 8);
        p += __shfl_xor(p, 16);
        p += __shfl_xor(p, 32);
        float mn = fmaxf(m, p);
        float sc = __expf(m - mn);
        float w  = __expf(p - mn);
        la = la * sc + w;
        a  = a * sc + w * x;
        m = mn;
    }
    float v = a / la + bf2f(bias[l]);
    if (*cnt >= 32) ((float*)outp)[(size_t)d * OUTC + l] = v;
    else            ((u16*)outp)[(size_t)d * OUTC + l]   = f2bf(v);
}

extern "C" void kernel_launch(void* const* d_in, const int* in_sizes, int n_in,
                              void* d_out, int out_size, void* d_ws, size_t ws_size,
                              hipStream_t stream)
{
    const void* x  = d_in[0];
    const int*  ei = (const int*)d_in[1];

    char* ws = (char*)d_ws;
    // layout (bytes), peak ~79.5 MB:
    u16* xl1     = (u16*)(ws + 0);          // 25.6 MB
    u16* xr1     = (u16*)(ws + 25600000);   // 25.6 MB
    u16* hbuf    = (u16*)(ws + 51200000);   // 25.6 MB
    u16* xl2     = (u16*)(ws + 0);          // overlay xl1 (dead after node1)
    u16* xr2     = (u16*)(ws + 6400000);
    int* hist    = (int*)(ws + 76800000);   // 200 KB
    int* rowptr  = (int*)(ws + 77000000);   // 200 KB
    int* off     = (int*)(ws + 77200000);   // 200 KB
    int* src_csr = (int*)(ws + 77400000);   // 1.8 MB -> ends 79.2M
    int* cnt     = (int*)(ws + 79200000);
    u16* prm     = (u16*)(ws + 79200064);   // ~200 KB converted params

    u16* Wl1   = prm + 0;
    u16* bl1   = prm + 32768;
    u16* Wr1   = prm + 33024;
    u16* br1   = prm + 65792;
    u16* att1  = prm + 66048;
    u16* bias1 = prm + 66304;
    u16* Wl2   = prm + 66560;
    u16* bl2   = prm + 82944;
    u16* Wr2   = prm + 83008;
    u16* br2   = prm + 99392;
    u16* att2  = prm + 99456;
    u16* bias2 = prm + 99520;

    // dtype detection + param conversion
    hipMemsetAsync(cnt, 0, 4, stream);
    detect_kernel<<<1, 256, 0, stream>>>((const unsigned*)x, cnt);
    const int psz[12] = {32768, 256, 32768, 256, 256, 256, 16384, 64, 16384, 64, 64, 64};
    u16* pdst[12] = {Wl1, bl1, Wr1, br1, att1, bias1, Wl2, bl2, Wr2, br2, att2, bias2};
    for (int i = 0; i < 12; ++i)
        convert_kernel<<<(psz[i] + 255) / 256, 256, 0, stream>>>(d_in[2 + i], pdst[i], psz[i], cnt);

    // CSR build (shared by both layers)
    hipMemsetAsync(hist, 0, 200000, stream);
    const int eb = (ET + 255) / 256;
    hist_kernel<<<eb, 256, 0, stream>>>(ei, hist);
    scan_kernel<<<1, 1024, 0, stream>>>(hist, rowptr, off);
    scatter_kernel<<<eb, 256, 0, stream>>>(ei, off, src_csr);

    // layer 1
    {
        dim3 g(N_NODES / 8, 2);   // MT=128 -> RPB=8
        linear_kernel<128, 256, 128><<<g, 256, 0, stream>>>((const u16*)x, Wl1, bl1, xl1, N_NODES, cnt, 1);
        linear_kernel<128, 256, 128><<<g, 256, 0, stream>>>((const u16*)x, Wr1, br1, xr1, N_NODES, cnt, 1);
    }
    const int nb = (N_NODES * 64 + 255) / 256;   // one wave per node
    node1_kernel<<<nb, 256, 0, stream>>>(xl1, xr1, rowptr, hist, src_csr, att1, bias1, hbuf);

    // layer 2
    {
        dim3 g(N_NODES / 16, 1);  // MT=64 -> RPB=16
        linear_kernel<256, 64, 64><<<g, 256, 0, stream>>>(hbuf, Wl2, bl2, xl2, N_NODES, cnt, 0);
        linear_kernel<256, 64, 64><<<g, 256, 0, stream>>>(hbuf, Wr2, br2, xr2, N_NODES, cnt, 0);
    }
    node2_kernel<<<nb, 256, 0, stream>>>(xl2, xr2, rowptr, hist, src_csr, att2, bias2, d_out, cnt);
}

// Round 5
// 362.271 us; speedup vs baseline: 6.2589x; 1.9393x over previous
//
#include <hip/hip_runtime.h>
#include <hip/hip_bf16.h>

typedef unsigned short u16;
typedef __attribute__((ext_vector_type(8))) short short8;
typedef __attribute__((ext_vector_type(4))) float floatx4;

#define N_NODES 50000
#define N_EDGES 400000
#define ET      450000   // edges + self loops
#define F_IN    128
#define C1      256      // H*HID
#define HID     64
#define OUTC    64
#define SLOPE   0.2f

__device__ __forceinline__ float bf2f(u16 v) {
    return __uint_as_float(((unsigned)v) << 16);
}
__device__ __forceinline__ u16 f2bf(float f) {   // round-to-nearest-even
    unsigned u = __float_as_uint(f);
    return (u16)((u + 0x7fffu + ((u >> 16) & 1u)) >> 16);
}

// ---------------- dtype detector (f32 vs bf16 input buffers) ----------------
__global__ __launch_bounds__(256) void detect_kernel(const unsigned* __restrict__ xw,
                                                     int* __restrict__ cnt)
{
    unsigned w = xw[threadIdx.x];
    unsigned aexp = (w >> 7) & 0xFFu;   // exponent field of low-half bf16
    if (aexp >= 170u || aexp <= 40u) atomicAdd(cnt, 1);
}

// ---------------- fused small-param convert (biases + att), 1280 elems ------
__global__ __launch_bounds__(256) void convert_small_kernel(
    const void* s0, const void* s1, const void* s2, const void* s3,
    const void* s4, const void* s5, const void* s6, const void* s7,
    u16* __restrict__ prm, const int* __restrict__ cnt)
{
    bool f32m = (*cnt >= 32);
    for (int t = threadIdx.x; t < 1280; t += 256) {
        const void* src; int local;
        if      (t < 256)  { src = s0; local = t; }
        else if (t < 512)  { src = s1; local = t - 256; }
        else if (t < 768)  { src = s2; local = t - 512; }
        else if (t < 1024) { src = s3; local = t - 768; }
        else if (t < 1088) { src = s4; local = t - 1024; }
        else if (t < 1152) { src = s5; local = t - 1088; }
        else if (t < 1216) { src = s6; local = t - 1152; }
        else               { src = s7; local = t - 1216; }
        prm[t] = f32m ? f2bf(((const float*)src)[local]) : ((const u16*)src)[local];
    }
}

// ---------------- W transpose+convert: Wt[n][k] = W[k][n] --------------------
// Wl1/Wr1: [128][256] -> 32768 each at 0 / 32768
// Wl2/Wr2: [256][64]  -> 16384 each at 65536 / 81920
__global__ __launch_bounds__(256) void convert_wt_kernel(
    const void* wl1, const void* wr1, const void* wl2, const void* wr2,
    u16* __restrict__ wt, const int* __restrict__ cnt)
{
    int t = blockIdx.x * 256 + threadIdx.x;   // 98304 total
    bool f32m = (*cnt >= 32);
    const void* src; int local, k, n, K, base;
    if (t < 32768)      { src = wl1; local = t;         k = local >> 8; n = local & 255; K = 128; base = 0; }
    else if (t < 65536) { src = wr1; local = t - 32768; k = local >> 8; n = local & 255; K = 128; base = 32768; }
    else if (t < 81920) { src = wl2; local = t - 65536; k = local >> 6; n = local & 63;  K = 256; base = 65536; }
    else                { src = wr2; local = t - 81920; k = local >> 6; n = local & 63;  K = 256; base = 81920; }
    u16 v = f32m ? f2bf(((const float*)src)[local]) : ((const u16*)src)[local];
    wt[base + n * K + k] = v;
}

// ---------------- CSR build (by dst) ----------------
__global__ __launch_bounds__(256) void hist_kernel(const int* __restrict__ ei,
                                                   int* __restrict__ hist)
{
    int t = blockIdx.x * 256 + threadIdx.x;
    if (t >= ET) return;
    int d = (t < N_EDGES) ? ei[N_EDGES + t] : t - N_EDGES;
    atomicAdd(&hist[d], 1);
}

// hierarchical scan: phase 1 — per-block exclusive scan + block sums
__global__ __launch_bounds__(256) void scan1_kernel(const int* __restrict__ hist,
                                                    int* __restrict__ rowptr,
                                                    int* __restrict__ bsum)
{
    int t = threadIdx.x;
    int i = blockIdx.x * 256 + t;
    int v = (i < N_NODES) ? hist[i] : 0;
    __shared__ int sd[256];
    sd[t] = v;
    __syncthreads();
    #pragma unroll
    for (int ofs = 1; ofs < 256; ofs <<= 1) {
        int u = (t >= ofs) ? sd[t - ofs] : 0;
        __syncthreads();
        sd[t] += u;
        __syncthreads();
    }
    if (i < N_NODES) rowptr[i] = sd[t] - v;   // exclusive within block
    if (t == 255) bsum[blockIdx.x] = sd[255];
}

// phase 2 — exclusive scan of the 196 block sums
__global__ __launch_bounds__(256) void scan2_kernel(int* __restrict__ bsum,
                                                    int* __restrict__ boff)
{
    int t = threadIdx.x;
    int v = (t < 196) ? bsum[t] : 0;
    __shared__ int sd[256];
    sd[t] = v;
    __syncthreads();
    #pragma unroll
    for (int ofs = 1; ofs < 256; ofs <<= 1) {
        int u = (t >= ofs) ? sd[t - ofs] : 0;
        __syncthreads();
        sd[t] += u;
        __syncthreads();
    }
    if (t < 196) boff[t] = sd[t] - v;
}

// phase 3 — add block offsets, duplicate into off
__global__ __launch_bounds__(256) void scan3_kernel(int* __restrict__ rowptr,
                                                    const int* __restrict__ boff,
                                                    int* __restrict__ off)
{
    int i = blockIdx.x * 256 + threadIdx.x;
    if (i >= N_NODES) return;
    int r = rowptr[i] + boff[blockIdx.x];
    rowptr[i] = r;
    off[i] = r;
}

__global__ __launch_bounds__(256) void scatter_kernel(const int* __restrict__ ei,
                                                      int* __restrict__ off,
                                                      int* __restrict__ src_csr)
{
    int t = blockIdx.x * 256 + threadIdx.x;
    if (t >= ET) return;
    int s, d;
    if (t < N_EDGES) { s = ei[t]; d = ei[N_EDGES + t]; } else { s = d = t - N_EDGES; }
    int pos = atomicAdd(&off[d], 1);
    src_csr[pos] = s;
}

// ---------------- MFMA GEMM: Y[r, ct*64+c] = X[r,:] @ W[:, ct*64+c] + B ------
// block = 256 threads = 4 waves; 64x64 output tile; BK=128 K-chunks.
// Wt is pre-transposed: Wt[n][k], row length K. A/B frags: contiguous 8xK bf16.
template<int K, int N>
__global__ __launch_bounds__(256) void lin_mfma_kernel(
    const u16* __restrict__ X, const u16* __restrict__ Wt,
    const u16* __restrict__ Bv, u16* __restrict__ Y, int nrows,
    const int* __restrict__ cnt, int dual)
{
    constexpr int BK = 128;
    constexpr int LDS_S = BK + 8;             // 272 B rows: 16B-aligned, conflict-softened
    __shared__ __align__(16) u16 sX[64 * LDS_S];
    __shared__ __align__(16) u16 sB[64 * LDS_S];

    const bool f32m = dual && (*cnt >= 32);
    const float* X32 = (const float*)X;

    const int row0 = blockIdx.x * 64;
    const int ct = blockIdx.y;
    const int wave = threadIdx.x >> 6;
    const int lane = threadIdx.x & 63;
    const int quad = lane >> 4;
    const int l16 = lane & 15;

    floatx4 acc0 = {0.f, 0.f, 0.f, 0.f}, acc1 = acc0, acc2 = acc0, acc3 = acc0;

    for (int kb = 0; kb < K / BK; ++kb) {
        const int k0 = kb * BK;
        // stage X tile (64 x 128), converting f32->bf16 if needed
        for (int i = threadIdx.x * 8; i < 64 * BK; i += 256 * 8) {
            int r = i >> 7, c = i & 127;
            int gr = row0 + r;
            u16* dst = &sX[r * LDS_S + c];
            if (f32m) {
                float4 v0 = make_float4(0.f, 0.f, 0.f, 0.f), v1 = v0;
                if (gr < nrows) {
                    v0 = *(const float4*)&X32[(size_t)gr * K + k0 + c];
                    v1 = *(const float4*)&X32[(size_t)gr * K + k0 + c + 4];
                }
                ushort4 p0, p1;
                p0.x = f2bf(v0.x); p0.y = f2bf(v0.y); p0.z = f2bf(v0.z); p0.w = f2bf(v0.w);
                p1.x = f2bf(v1.x); p1.y = f2bf(v1.y); p1.z = f2bf(v1.z); p1.w = f2bf(v1.w);
                *(ushort4*)dst = p0;
                *(ushort4*)(dst + 4) = p1;
            } else {
                uint4 v = {0u, 0u, 0u, 0u};
                if (gr < nrows) v = *(const uint4*)&X[(size_t)gr * K + k0 + c];
                *(uint4*)dst = v;
            }
        }
        // stage Wt tile (64 cols x 128 k), always bf16
        for (int i = threadIdx.x * 8; i < 64 * BK; i += 256 * 8) {
            int n = i >> 7, c = i & 127;
            *(uint4*)&sB[n * LDS_S + c] =
                *(const uint4*)&Wt[(size_t)(ct * 64 + n) * K + k0 + c];
        }
        __syncthreads();

        #pragma unroll
        for (int kk = 0; kk < 4; ++kk) {
            short8 a = *(const short8*)&sX[(wave * 16 + l16) * LDS_S + kk * 32 + quad * 8];
            short8 b0 = *(const short8*)&sB[(0 * 16 + l16) * LDS_S + kk * 32 + quad * 8];
            short8 b1 = *(const short8*)&sB[(1 * 16 + l16) * LDS_S + kk * 32 + quad * 8];
            short8 b2 = *(const short8*)&sB[(2 * 16 + l16) * LDS_S + kk * 32 + quad * 8];
            short8 b3 = *(const short8*)&sB[(3 * 16 + l16) * LDS_S + kk * 32 + quad * 8];
            acc0 = __builtin_amdgcn_mfma_f32_16x16x32_bf16(a, b0, acc0, 0, 0, 0);
            acc1 = __builtin_amdgcn_mfma_f32_16x16x32_bf16(a, b1, acc1, 0, 0, 0);
            acc2 = __builtin_amdgcn_mfma_f32_16x16x32_bf16(a, b2, acc2, 0, 0, 0);
            acc3 = __builtin_amdgcn_mfma_f32_16x16x32_bf16(a, b3, acc3, 0, 0, 0);
        }
        __syncthreads();
    }

    // epilogue: D row = quad*4+reg, col = lane&15 (verified m89/m91 mapping)
    const int rbase = row0 + wave * 16 + quad * 4;
    #pragma unroll
    for (int c = 0; c < 4; ++c) {
        const floatx4 av = (c == 0) ? acc0 : (c == 1) ? acc1 : (c == 2) ? acc2 : acc3;
        const int col = ct * 64 + c * 16 + l16;
        const float bv = bf2f(Bv[col]);
        #pragma unroll
        for (int r = 0; r < 4; ++r) {
            int row = rbase + r;
            if (row < nrows) Y[(size_t)row * N + col] = f2bf(av[r] + bv);
        }
    }
}

// ---------------- layer 1 fused per-node GATv2 (4 heads x 64 ch) ----------------
__global__ __launch_bounds__(256) void node1_kernel(
    const u16* __restrict__ xl, const u16* __restrict__ xr,
    const int* __restrict__ rowptr, const int* __restrict__ hist,
    const int* __restrict__ src_csr, const u16* __restrict__ att,
    const u16* __restrict__ bias, u16* __restrict__ hout)
{
    int gid = blockIdx.x * 256 + threadIdx.x;
    int d = gid >> 6, l = gid & 63;
    if (d >= N_NODES) return;
    const int start = rowptr[d];
    const int deg = hist[d];

    ushort4 av = *(const ushort4*)&att[l * 4];
    const float at0 = bf2f(av.x), at1 = bf2f(av.y), at2 = bf2f(av.z), at3 = bf2f(av.w);
    ushort4 xrv = *(const ushort4*)&xr[(size_t)d * C1 + l * 4];
    const float r0 = bf2f(xrv.x), r1 = bf2f(xrv.y), r2 = bf2f(xrv.z), r3 = bf2f(xrv.w);

    float m = -1e30f, la = 0.f;
    float a0 = 0.f, a1 = 0.f, a2 = 0.f, a3 = 0.f;
    for (int j = 0; j < deg; ++j) {
        int s = src_csr[start + j];
        ushort4 xv = *(const ushort4*)&xl[(size_t)s * C1 + l * 4];
        float x0 = bf2f(xv.x), x1 = bf2f(xv.y), x2 = bf2f(xv.z), x3 = bf2f(xv.w);
        float t, p = 0.f;
        t = x0 + r0; t = t > 0.f ? t : SLOPE * t; p += t * at0;
        t = x1 + r1; t = t > 0.f ? t : SLOPE * t; p += t * at1;
        t = x2 + r2; t = t > 0.f ? t : SLOPE * t; p += t * at2;
        t = x3 + r3; t = t > 0.f ? t : SLOPE * t; p += t * at3;
        p += __shfl_xor(p, 1);
        p += __shfl_xor(p, 2);
        p += __shfl_xor(p, 4);
        p += __shfl_xor(p, 8);
        float mn = fmaxf(m, p);
        float sc = __expf(m - mn);
        float w  = __expf(p - mn);
        la = la * sc + w;
        a0 = a0 * sc + w * x0;
        a1 = a1 * sc + w * x1;
        a2 = a2 * sc + w * x2;
        a3 = a3 * sc + w * x3;
        m = mn;
    }
    const float inv = 1.f / la;
    const int c = l * 4;
    float v0 = a0 * inv + bf2f(bias[c + 0]);
    float v1 = a1 * inv + bf2f(bias[c + 1]);
    float v2 = a2 * inv + bf2f(bias[c + 2]);
    float v3 = a3 * inv + bf2f(bias[c + 3]);
    v0 = v0 > 0.f ? v0 : __expf(fminf(v0, 0.f)) - 1.f;
    v1 = v1 > 0.f ? v1 : __expf(fminf(v1, 0.f)) - 1.f;
    v2 = v2 > 0.f ? v2 : __expf(fminf(v2, 0.f)) - 1.f;
    v3 = v3 > 0.f ? v3 : __expf(fminf(v3, 0.f)) - 1.f;
    ushort4 o;
    o.x = f2bf(v0); o.y = f2bf(v1); o.z = f2bf(v2); o.w = f2bf(v3);
    *(ushort4*)&hout[(size_t)d * C1 + c] = o;
}

// ---------------- layer 2 fused per-node GATv2 (1 head x 64 ch) ----------------
__global__ __launch_bounds__(256) void node2_kernel(
    const u16* __restrict__ xl, const u16* __restrict__ xr,
    const int* __restrict__ rowptr, const int* __restrict__ hist,
    const int* __restrict__ src_csr, const u16* __restrict__ att,
    const u16* __restrict__ bias, void* __restrict__ outp,
    const int* __restrict__ cnt)
{
    int gid = blockIdx.x * 256 + threadIdx.x;
    int d = gid >> 6, l = gid & 63;
    if (d >= N_NODES) return;
    const int start = rowptr[d];
    const int deg = hist[d];

    const float at = bf2f(att[l]);
    const float r  = bf2f(xr[(size_t)d * OUTC + l]);

    float m = -1e30f, la = 0.f, a = 0.f;
    for (int j = 0; j < deg; ++j) {
        int s = src_csr[start + j];
        float x = bf2f(xl[(size_t)s * OUTC + l]);
        float t = x + r;
        t = t > 0.f ? t : SLOPE * t;
        float p = t * at;
        p += __shfl_xor(p, 1);
        p += __shfl_xor(p, 2);
        p += __shfl_xor(p, 4);
        p += __shfl_xor(p, 8);
        p += __shfl_xor(p, 16);
        p += __shfl_xor(p, 32);
        float mn = fmaxf(m, p);
        float sc = __expf(m - mn);
        float w  = __expf(p - mn);
        la = la * sc + w;
        a  = a * sc + w * x;
        m = mn;
    }
    float v = a / la + bf2f(bias[l]);
    if (*cnt >= 32) ((float*)outp)[(size_t)d * OUTC + l] = v;
    else            ((u16*)outp)[(size_t)d * OUTC + l]   = f2bf(v);
}

extern "C" void kernel_launch(void* const* d_in, const int* in_sizes, int n_in,
                              void* d_out, int out_size, void* d_ws, size_t ws_size,
                              hipStream_t stream)
{
    const void* x  = d_in[0];
    const int*  ei = (const int*)d_in[1];

    char* ws = (char*)d_ws;
    u16* xl1     = (u16*)(ws + 0);          // 25.6 MB
    u16* xr1     = (u16*)(ws + 25600000);   // 25.6 MB
    u16* hbuf    = (u16*)(ws + 51200000);   // 25.6 MB
    u16* xl2     = (u16*)(ws + 0);          // overlay xl1 (dead after node1)
    u16* xr2     = (u16*)(ws + 6400000);
    int* hist    = (int*)(ws + 76800000);
    int* rowptr  = (int*)(ws + 77000000);
    int* off     = (int*)(ws + 77200000);
    int* src_csr = (int*)(ws + 77400000);   // 1.8 MB
    int* cnt     = (int*)(ws + 79200000);
    u16* prm     = (u16*)(ws + 79200064);   // 1280 u16 small params
    u16* wt      = (u16*)(ws + 79210240);   // 98304 u16 transposed weights
    int* bsum    = (int*)(ws + 79410000);
    int* boff    = (int*)(ws + 79411024);

    // small-param element offsets inside prm
    u16* bl1   = prm + 0;
    u16* br1   = prm + 256;
    u16* att1  = prm + 512;
    u16* bias1 = prm + 768;
    u16* bl2   = prm + 1024;
    u16* br2   = prm + 1088;
    u16* att2  = prm + 1152;
    u16* bias2 = prm + 1216;
    u16* wtl1  = wt + 0;
    u16* wtr1  = wt + 32768;
    u16* wtl2  = wt + 65536;
    u16* wtr2  = wt + 81920;

    // dtype detection + param conversion
    hipMemsetAsync(cnt, 0, 4, stream);
    detect_kernel<<<1, 256, 0, stream>>>((const unsigned*)x, cnt);
    convert_small_kernel<<<1, 256, 0, stream>>>(
        d_in[3], d_in[5], d_in[6], d_in[7], d_in[9], d_in[11], d_in[12], d_in[13],
        prm, cnt);
    convert_wt_kernel<<<98304 / 256, 256, 0, stream>>>(
        d_in[2], d_in[4], d_in[8], d_in[10], wt, cnt);

    // CSR build
    hipMemsetAsync(hist, 0, 200000, stream);
    const int eb = (ET + 255) / 256;
    hist_kernel<<<eb, 256, 0, stream>>>(ei, hist);
    scan1_kernel<<<196, 256, 0, stream>>>(hist, rowptr, bsum);
    scan2_kernel<<<1, 256, 0, stream>>>(bsum, boff);
    scan3_kernel<<<196, 256, 0, stream>>>(rowptr, boff, off);
    scatter_kernel<<<eb, 256, 0, stream>>>(ei, off, src_csr);

    // layer 1 linears (MFMA), X possibly f32
    {
        dim3 g((N_NODES + 63) / 64, 4);   // 782 x 4 col-tiles
        lin_mfma_kernel<128, 256><<<g, 256, 0, stream>>>((const u16*)x, wtl1, bl1, xl1, N_NODES, cnt, 1);
        lin_mfma_kernel<128, 256><<<g, 256, 0, stream>>>((const u16*)x, wtr1, br1, xr1, N_NODES, cnt, 1);
    }
    const int nb = (N_NODES * 64 + 255) / 256;
    node1_kernel<<<nb, 256, 0, stream>>>(xl1, xr1, rowptr, hist, src_csr, att1, bias1, hbuf);

    // layer 2 linears (MFMA), input bf16
    {
        dim3 g((N_NODES + 63) / 64, 1);
        lin_mfma_kernel<256, 64><<<g, 256, 0, stream>>>(hbuf, wtl2, bl2, xl2, N_NODES, cnt, 0);
        lin_mfma_kernel<256, 64><<<g, 256, 0, stream>>>(hbuf, wtr2, br2, xr2, N_NODES, cnt, 0);
    }
    node2_kernel<<<nb, 256, 0, stream>>>(xl2, xr2, rowptr, hist, src_csr, att2, bias2, d_out, cnt);
}

// Round 6
// 310.211 us; speedup vs baseline: 7.3092x; 1.1678x over previous
//
#include <hip/hip_runtime.h>
#include <hip/hip_bf16.h>

typedef unsigned short u16;
typedef __attribute__((ext_vector_type(8))) short short8;
typedef __attribute__((ext_vector_type(4))) float floatx4;

#define N_NODES 50000
#define N_EDGES 400000
#define ET      450000   // edges + self loops
#define F_IN    128
#define C1      256      // H*HID
#define HID     64
#define OUTC    64
#define SLOPE   0.2f

__device__ __forceinline__ float bf2f(u16 v) {
    return __uint_as_float(((unsigned)v) << 16);
}
__device__ __forceinline__ u16 f2bf(float f) {   // round-to-nearest-even
    unsigned u = __float_as_uint(f);
    return (u16)((u + 0x7fffu + ((u >> 16) & 1u)) >> 16);
}

// ---------------- dtype detector (f32 vs bf16 input buffers) ----------------
__global__ __launch_bounds__(256) void detect_kernel(const unsigned* __restrict__ xw,
                                                     int* __restrict__ cnt)
{
    unsigned w = xw[threadIdx.x];
    unsigned aexp = (w >> 7) & 0xFFu;   // exponent field of low-half bf16
    if (aexp >= 170u || aexp <= 40u) atomicAdd(cnt, 1);
}

// ---------------- fused param convert --------------------------------------
// blocks 0..383: transpose W into wt ([2][256][128] for L1, [2][64][256] for L2)
// block 384: small params (biases + att) -> prm
__global__ __launch_bounds__(256) void convert_all_kernel(
    const void* wl1, const void* wr1, const void* wl2, const void* wr2,
    const void* s0, const void* s1, const void* s2, const void* s3,
    const void* s4, const void* s5, const void* s6, const void* s7,
    u16* __restrict__ wt, u16* __restrict__ prm, const int* __restrict__ cnt)
{
    bool f32m = (*cnt >= 32);
    if (blockIdx.x == 384) {
        for (int t = threadIdx.x; t < 1280; t += 256) {
            const void* src; int local;
            if      (t < 256)  { src = s0; local = t; }
            else if (t < 512)  { src = s1; local = t - 256; }
            else if (t < 768)  { src = s2; local = t - 512; }
            else if (t < 1024) { src = s3; local = t - 768; }
            else if (t < 1088) { src = s4; local = t - 1024; }
            else if (t < 1152) { src = s5; local = t - 1088; }
            else if (t < 1216) { src = s6; local = t - 1152; }
            else               { src = s7; local = t - 1216; }
            prm[t] = f32m ? f2bf(((const float*)src)[local]) : ((const u16*)src)[local];
        }
        return;
    }
    int t = blockIdx.x * 256 + threadIdx.x;   // 98304 total
    const void* src; int local, k, n, K, base;
    if (t < 32768)      { src = wl1; local = t;         k = local >> 8; n = local & 255; K = 128; base = 0; }
    else if (t < 65536) { src = wr1; local = t - 32768; k = local >> 8; n = local & 255; K = 128; base = 32768; }
    else if (t < 81920) { src = wl2; local = t - 65536; k = local >> 6; n = local & 63;  K = 256; base = 65536; }
    else                { src = wr2; local = t - 81920; k = local >> 6; n = local & 63;  K = 256; base = 81920; }
    u16 v = f32m ? f2bf(((const float*)src)[local]) : ((const u16*)src)[local];
    wt[base + n * K + k] = v;
}

// ---------------- CSR build (by dst) ----------------
__global__ __launch_bounds__(256) void hist_kernel(const int* __restrict__ ei,
                                                   int* __restrict__ hist)
{
    int t = blockIdx.x * 256 + threadIdx.x;
    if (t >= ET) return;
    int d = (t < N_EDGES) ? ei[N_EDGES + t] : t - N_EDGES;
    atomicAdd(&hist[d], 1);
}

__global__ __launch_bounds__(256) void scan1_kernel(const int* __restrict__ hist,
                                                    int* __restrict__ rowptr,
                                                    int* __restrict__ bsum)
{
    int t = threadIdx.x;
    int i = blockIdx.x * 256 + t;
    int v = (i < N_NODES) ? hist[i] : 0;
    __shared__ int sd[256];
    sd[t] = v;
    __syncthreads();
    #pragma unroll
    for (int ofs = 1; ofs < 256; ofs <<= 1) {
        int u = (t >= ofs) ? sd[t - ofs] : 0;
        __syncthreads();
        sd[t] += u;
        __syncthreads();
    }
    if (i < N_NODES) rowptr[i] = sd[t] - v;
    if (t == 255) bsum[blockIdx.x] = sd[255];
}

__global__ __launch_bounds__(256) void scan2_kernel(int* __restrict__ bsum,
                                                    int* __restrict__ boff)
{
    int t = threadIdx.x;
    int v = (t < 196) ? bsum[t] : 0;
    __shared__ int sd[256];
    sd[t] = v;
    __syncthreads();
    #pragma unroll
    for (int ofs = 1; ofs < 256; ofs <<= 1) {
        int u = (t >= ofs) ? sd[t - ofs] : 0;
        __syncthreads();
        sd[t] += u;
        __syncthreads();
    }
    if (t < 196) boff[t] = sd[t] - v;
}

__global__ __launch_bounds__(256) void scan3_kernel(int* __restrict__ rowptr,
                                                    const int* __restrict__ boff,
                                                    int* __restrict__ off)
{
    int i = blockIdx.x * 256 + threadIdx.x;
    if (i >= N_NODES) return;
    int r = rowptr[i] + boff[blockIdx.x];
    rowptr[i] = r;
    off[i] = r;
}

__global__ __launch_bounds__(256) void scatter_kernel(const int* __restrict__ ei,
                                                      int* __restrict__ off,
                                                      int* __restrict__ src_csr)
{
    int t = blockIdx.x * 256 + threadIdx.x;
    if (t >= ET) return;
    int s, d;
    if (t < N_EDGES) { s = ei[t]; d = ei[N_EDGES + t]; } else { s = d = t - N_EDGES; }
    int pos = atomicAdd(&off[d], 1);
    src_csr[pos] = s;
}

// ---------------- fused layer-1 linear: xl1 AND xr1 from one X staging ------
// K=128, N=256. Block: 64 rows, 4 waves. X staged once; loop side x 4 chunks.
__global__ __launch_bounds__(256) void lin1_fused_kernel(
    const u16* __restrict__ X, const u16* __restrict__ Wt,   // Wt: [2][256][128]
    const u16* __restrict__ bl, const u16* __restrict__ br,
    u16* __restrict__ Yl, u16* __restrict__ Yr, int nrows,
    const int* __restrict__ cnt)
{
    constexpr int K = 128, N = 256, LS = K + 8;   // 136 u16 rows (272 B, 16B-aligned)
    __shared__ __align__(16) u16 sX[64 * LS];
    __shared__ __align__(16) u16 sW[64 * LS];
    const bool f32m = (*cnt >= 32);
    const float* X32 = (const float*)X;
    const int row0 = blockIdx.x * 64;
    const int wave = threadIdx.x >> 6, lane = threadIdx.x & 63;
    const int quad = lane >> 4, l16 = lane & 15;

    // stage X tile (64 x 128), converting f32->bf16 if needed
    for (int i = threadIdx.x * 8; i < 64 * K; i += 2048) {
        int r = i >> 7, c = i & 127;
        int gr = row0 + r;
        u16* dst = &sX[r * LS + c];
        if (f32m) {
            float4 v0 = make_float4(0.f, 0.f, 0.f, 0.f), v1 = v0;
            if (gr < nrows) {
                v0 = *(const float4*)&X32[(size_t)gr * K + c];
                v1 = *(const float4*)&X32[(size_t)gr * K + c + 4];
            }
            ushort4 p0, p1;
            p0.x = f2bf(v0.x); p0.y = f2bf(v0.y); p0.z = f2bf(v0.z); p0.w = f2bf(v0.w);
            p1.x = f2bf(v1.x); p1.y = f2bf(v1.y); p1.z = f2bf(v1.z); p1.w = f2bf(v1.w);
            *(ushort4*)dst = p0;
            *(ushort4*)(dst + 4) = p1;
        } else {
            uint4 v = {0u, 0u, 0u, 0u};
            if (gr < nrows) v = *(const uint4*)&X[(size_t)gr * K + c];
            *(uint4*)dst = v;
        }
    }

    for (int side = 0; side < 2; ++side) {
        const u16* wbase = Wt + side * (N * K);
        const u16* bias  = side ? br : bl;
        u16* Y = side ? Yr : Yl;
        for (int ch = 0; ch < 4; ++ch) {
            __syncthreads();   // protect sW from previous iteration's readers
            for (int i = threadIdx.x * 8; i < 64 * K; i += 2048) {
                int n = i >> 7, c = i & 127;
                *(uint4*)&sW[n * LS + c] = *(const uint4*)&wbase[(size_t)(ch * 64 + n) * K + c];
            }
            __syncthreads();
            floatx4 acc0 = {0.f, 0.f, 0.f, 0.f}, acc1 = acc0, acc2 = acc0, acc3 = acc0;
            #pragma unroll
            for (int kk = 0; kk < 4; ++kk) {
                short8 a  = *(const short8*)&sX[(wave * 16 + l16) * LS + kk * 32 + quad * 8];
                short8 b0 = *(const short8*)&sW[(l16) * LS + kk * 32 + quad * 8];
                short8 b1 = *(const short8*)&sW[(16 + l16) * LS + kk * 32 + quad * 8];
                short8 b2 = *(const short8*)&sW[(32 + l16) * LS + kk * 32 + quad * 8];
                short8 b3 = *(const short8*)&sW[(48 + l16) * LS + kk * 32 + quad * 8];
                acc0 = __builtin_amdgcn_mfma_f32_16x16x32_bf16(a, b0, acc0, 0, 0, 0);
                acc1 = __builtin_amdgcn_mfma_f32_16x16x32_bf16(a, b1, acc1, 0, 0, 0);
                acc2 = __builtin_amdgcn_mfma_f32_16x16x32_bf16(a, b2, acc2, 0, 0, 0);
                acc3 = __builtin_amdgcn_mfma_f32_16x16x32_bf16(a, b3, acc3, 0, 0, 0);
            }
            const int rbase = row0 + wave * 16 + quad * 4;
            #pragma unroll
            for (int cf = 0; cf < 4; ++cf) {
                const floatx4 av = (cf == 0) ? acc0 : (cf == 1) ? acc1 : (cf == 2) ? acc2 : acc3;
                const int col = ch * 64 + cf * 16 + l16;
                const float bv = bf2f(bias[col]);
                #pragma unroll
                for (int r = 0; r < 4; ++r) {
                    int row = rbase + r;
                    if (row < nrows) Y[(size_t)row * N + col] = f2bf(av[r] + bv);
                }
            }
        }
    }
}

// ---------------- fused layer-2 linear: xl2 AND xr2 from one X staging ------
// K=256, N=64. Block: 64 rows, 4 waves. X (bf16) staged once; loop 2 sides.
__global__ __launch_bounds__(256) void lin2_fused_kernel(
    const u16* __restrict__ X, const u16* __restrict__ Wt,   // Wt: [2][64][256]
    const u16* __restrict__ bl, const u16* __restrict__ br,
    u16* __restrict__ Yl, u16* __restrict__ Yr, int nrows)
{
    constexpr int K = 256, N = 64, LS = K + 8;   // 264 u16 rows (528 B)
    __shared__ __align__(16) u16 sX[64 * LS];
    __shared__ __align__(16) u16 sW[64 * LS];
    const int row0 = blockIdx.x * 64;
    const int wave = threadIdx.x >> 6, lane = threadIdx.x & 63;
    const int quad = lane >> 4, l16 = lane & 15;

    for (int i = threadIdx.x * 8; i < 64 * K; i += 2048) {
        int r = i >> 8, c = i & 255;
        int gr = row0 + r;
        uint4 v = {0u, 0u, 0u, 0u};
        if (gr < nrows) v = *(const uint4*)&X[(size_t)gr * K + c];
        *(uint4*)&sX[r * LS + c] = v;
    }

    for (int side = 0; side < 2; ++side) {
        const u16* wbase = Wt + side * (N * K);
        const u16* bias  = side ? br : bl;
        u16* Y = side ? Yr : Yl;
        __syncthreads();
        for (int i = threadIdx.x * 8; i < 64 * K; i += 2048) {
            int n = i >> 8, c = i & 255;
            *(uint4*)&sW[n * LS + c] = *(const uint4*)&wbase[(size_t)n * K + c];
        }
        __syncthreads();
        floatx4 acc0 = {0.f, 0.f, 0.f, 0.f}, acc1 = acc0, acc2 = acc0, acc3 = acc0;
        #pragma unroll
        for (int kk = 0; kk < 8; ++kk) {
            short8 a  = *(const short8*)&sX[(wave * 16 + l16) * LS + kk * 32 + quad * 8];
            short8 b0 = *(const short8*)&sW[(l16) * LS + kk * 32 + quad * 8];
            short8 b1 = *(const short8*)&sW[(16 + l16) * LS + kk * 32 + quad * 8];
            short8 b2 = *(const short8*)&sW[(32 + l16) * LS + kk * 32 + quad * 8];
            short8 b3 = *(const short8*)&sW[(48 + l16) * LS + kk * 32 + quad * 8];
            acc0 = __builtin_amdgcn_mfma_f32_16x16x32_bf16(a, b0, acc0, 0, 0, 0);
            acc1 = __builtin_amdgcn_mfma_f32_16x16x32_bf16(a, b1, acc1, 0, 0, 0);
            acc2 = __builtin_amdgcn_mfma_f32_16x16x32_bf16(a, b2, acc2, 0, 0, 0);
            acc3 = __builtin_amdgcn_mfma_f32_16x16x32_bf16(a, b3, acc3, 0, 0, 0);
        }
        const int rbase = row0 + wave * 16 + quad * 4;
        #pragma unroll
        for (int cf = 0; cf < 4; ++cf) {
            const floatx4 av = (cf == 0) ? acc0 : (cf == 1) ? acc1 : (cf == 2) ? acc2 : acc3;
            const int col = cf * 16 + l16;
            const float bv = bf2f(bias[col]);
            #pragma unroll
            for (int r = 0; r < 4; ++r) {
                int row = rbase + r;
                if (row < nrows) Y[(size_t)row * N + col] = f2bf(av[r] + bv);
            }
        }
    }
}

// ---------------- layer 1 fused per-node GATv2 (4 heads x 64 ch) ----------------
// one wave per node; lane l: head h=l>>4, channels [4l, 4l+4)
// pairwise online softmax: 2 edges per iteration, single rescale.
__global__ __launch_bounds__(256) void node1_kernel(
    const u16* __restrict__ xl, const u16* __restrict__ xr,
    const int* __restrict__ rowptr, const int* __restrict__ hist,
    const int* __restrict__ src_csr, const u16* __restrict__ att,
    const u16* __restrict__ bias, u16* __restrict__ hout)
{
    int gid = blockIdx.x * 256 + threadIdx.x;
    int d = gid >> 6, l = gid & 63;
    if (d >= N_NODES) return;
    const int start = rowptr[d];
    const int deg = hist[d];

    ushort4 av = *(const ushort4*)&att[l * 4];
    const float at0 = bf2f(av.x), at1 = bf2f(av.y), at2 = bf2f(av.z), at3 = bf2f(av.w);
    ushort4 xrv = *(const ushort4*)&xr[(size_t)d * C1 + l * 4];
    const float r0 = bf2f(xrv.x), r1 = bf2f(xrv.y), r2 = bf2f(xrv.z), r3 = bf2f(xrv.w);

    float m = -1e30f, la = 0.f;
    float a0 = 0.f, a1 = 0.f, a2 = 0.f, a3 = 0.f;
    int j = 0;
    for (; j + 2 <= deg; j += 2) {
        int s0 = src_csr[start + j];
        int s1 = src_csr[start + j + 1];
        ushort4 u0 = *(const ushort4*)&xl[(size_t)s0 * C1 + l * 4];
        ushort4 u1 = *(const ushort4*)&xl[(size_t)s1 * C1 + l * 4];
        float x00 = bf2f(u0.x), x01 = bf2f(u0.y), x02 = bf2f(u0.z), x03 = bf2f(u0.w);
        float x10 = bf2f(u1.x), x11 = bf2f(u1.y), x12 = bf2f(u1.z), x13 = bf2f(u1.w);
        float t, p0 = 0.f, p1 = 0.f;
        t = x00 + r0; t = t > 0.f ? t : SLOPE * t; p0 += t * at0;
        t = x01 + r1; t = t > 0.f ? t : SLOPE * t; p0 += t * at1;
        t = x02 + r2; t = t > 0.f ? t : SLOPE * t; p0 += t * at2;
        t = x03 + r3; t = t > 0.f ? t : SLOPE * t; p0 += t * at3;
        t = x10 + r0; t = t > 0.f ? t : SLOPE * t; p1 += t * at0;
        t = x11 + r1; t = t > 0.f ? t : SLOPE * t; p1 += t * at1;
        t = x12 + r2; t = t > 0.f ? t : SLOPE * t; p1 += t * at2;
        t = x13 + r3; t = t > 0.f ? t : SLOPE * t; p1 += t * at3;
        p0 += __shfl_xor(p0, 1); p1 += __shfl_xor(p1, 1);
        p0 += __shfl_xor(p0, 2); p1 += __shfl_xor(p1, 2);
        p0 += __shfl_xor(p0, 4); p1 += __shfl_xor(p1, 4);
        p0 += __shfl_xor(p0, 8); p1 += __shfl_xor(p1, 8);
        float mn = fmaxf(m, fmaxf(p0, p1));
        float sc = __expf(m - mn);
        float w0 = __expf(p0 - mn);
        float w1 = __expf(p1 - mn);
        la = la * sc + w0 + w1;
        a0 = a0 * sc + w0 * x00 + w1 * x10;
        a1 = a1 * sc + w0 * x01 + w1 * x11;
        a2 = a2 * sc + w0 * x02 + w1 * x12;
        a3 = a3 * sc + w0 * x03 + w1 * x13;
        m = mn;
    }
    if (j < deg) {
        int s = src_csr[start + j];
        ushort4 xv = *(const ushort4*)&xl[(size_t)s * C1 + l * 4];
        float x0 = bf2f(xv.x), x1 = bf2f(xv.y), x2 = bf2f(xv.z), x3 = bf2f(xv.w);
        float t, p = 0.f;
        t = x0 + r0; t = t > 0.f ? t : SLOPE * t; p += t * at0;
        t = x1 + r1; t = t > 0.f ? t : SLOPE * t; p += t * at1;
        t = x2 + r2; t = t > 0.f ? t : SLOPE * t; p += t * at2;
        t = x3 + r3; t = t > 0.f ? t : SLOPE * t; p += t * at3;
        p += __shfl_xor(p, 1);
        p += __shfl_xor(p, 2);
        p += __shfl_xor(p, 4);
        p += __shfl_xor(p, 8);
        float mn = fmaxf(m, p);
        float sc = __expf(m - mn);
        float w  = __expf(p - mn);
        la = la * sc + w;
        a0 = a0 * sc + w * x0;
        a1 = a1 * sc + w * x1;
        a2 = a2 * sc + w * x2;
        a3 = a3 * sc + w * x3;
    }
    const float inv = 1.f / la;
    const int c = l * 4;
    float v0 = a0 * inv + bf2f(bias[c + 0]);
    float v1 = a1 * inv + bf2f(bias[c + 1]);
    float v2 = a2 * inv + bf2f(bias[c + 2]);
    float v3 = a3 * inv + bf2f(bias[c + 3]);
    v0 = v0 > 0.f ? v0 : __expf(fminf(v0, 0.f)) - 1.f;
    v1 = v1 > 0.f ? v1 : __expf(fminf(v1, 0.f)) - 1.f;
    v2 = v2 > 0.f ? v2 : __expf(fminf(v2, 0.f)) - 1.f;
    v3 = v3 > 0.f ? v3 : __expf(fminf(v3, 0.f)) - 1.f;
    ushort4 o;
    o.x = f2bf(v0); o.y = f2bf(v1); o.z = f2bf(v2); o.w = f2bf(v3);
    *(ushort4*)&hout[(size_t)d * C1 + c] = o;
}

// ---------------- layer 2 fused per-node GATv2 (1 head x 64 ch) ----------------
__global__ __launch_bounds__(256) void node2_kernel(
    const u16* __restrict__ xl, const u16* __restrict__ xr,
    const int* __restrict__ rowptr, const int* __restrict__ hist,
    const int* __restrict__ src_csr, const u16* __restrict__ att,
    const u16* __restrict__ bias, void* __restrict__ outp,
    const int* __restrict__ cnt)
{
    int gid = blockIdx.x * 256 + threadIdx.x;
    int d = gid >> 6, l = gid & 63;
    if (d >= N_NODES) return;
    const int start = rowptr[d];
    const int deg = hist[d];

    const float at = bf2f(att[l]);
    const float r  = bf2f(xr[(size_t)d * OUTC + l]);

    float m = -1e30f, la = 0.f, a = 0.f;
    for (int j = 0; j < deg; ++j) {
        int s = src_csr[start + j];
        float x = bf2f(xl[(size_t)s * OUTC + l]);
        float t = x + r;
        t = t > 0.f ? t : SLOPE * t;
        float p = t * at;
        p += __shfl_xor(p, 1);
        p += __shfl_xor(p, 2);
        p += __shfl_xor(p, 4);
        p += __shfl_xor(p, 8);
        p += __shfl_xor(p, 16);
        p += __shfl_xor(p, 32);
        float mn = fmaxf(m, p);
        float sc = __expf(m - mn);
        float w  = __expf(p - mn);
        la = la * sc + w;
        a  = a * sc + w * x;
        m = mn;
    }
    float v = a / la + bf2f(bias[l]);
    if (*cnt >= 32) ((float*)outp)[(size_t)d * OUTC + l] = v;
    else            ((u16*)outp)[(size_t)d * OUTC + l]   = f2bf(v);
}

extern "C" void kernel_launch(void* const* d_in, const int* in_sizes, int n_in,
                              void* d_out, int out_size, void* d_ws, size_t ws_size,
                              hipStream_t stream)
{
    const void* x  = d_in[0];
    const int*  ei = (const int*)d_in[1];

    char* ws = (char*)d_ws;
    u16* xl1     = (u16*)(ws + 0);          // 25.6 MB
    u16* xr1     = (u16*)(ws + 25600000);   // 25.6 MB
    u16* hbuf    = (u16*)(ws + 51200000);   // 25.6 MB
    u16* xl2     = (u16*)(ws + 0);          // overlay xl1 (dead after node1)
    u16* xr2     = (u16*)(ws + 6400000);
    int* hist    = (int*)(ws + 76800000);
    int* rowptr  = (int*)(ws + 77000000);
    int* off     = (int*)(ws + 77200000);
    int* src_csr = (int*)(ws + 77400000);   // 1.8 MB
    int* cnt     = (int*)(ws + 79200000);
    u16* prm     = (u16*)(ws + 79200064);   // 1280 u16 small params
    u16* wt      = (u16*)(ws + 79210240);   // 98304 u16 transposed weights
    int* bsum    = (int*)(ws + 79410000);
    int* boff    = (int*)(ws + 79411024);

    u16* bl1   = prm + 0;
    u16* br1   = prm + 256;
    u16* att1  = prm + 512;
    u16* bias1 = prm + 768;
    u16* bl2   = prm + 1024;
    u16* br2   = prm + 1088;
    u16* att2  = prm + 1152;
    u16* bias2 = prm + 1216;
    u16* wt1   = wt + 0;       // [2][256][128]
    u16* wt2   = wt + 65536;   // [2][64][256]

    // dtype detection + param conversion (one fused dispatch)
    hipMemsetAsync(cnt, 0, 4, stream);
    detect_kernel<<<1, 256, 0, stream>>>((const unsigned*)x, cnt);
    convert_all_kernel<<<385, 256, 0, stream>>>(
        d_in[2], d_in[4], d_in[8], d_in[10],
        d_in[3], d_in[5], d_in[6], d_in[7], d_in[9], d_in[11], d_in[12], d_in[13],
        wt, prm, cnt);

    // CSR build
    hipMemsetAsync(hist, 0, 200000, stream);
    const int eb = (ET + 255) / 256;
    hist_kernel<<<eb, 256, 0, stream>>>(ei, hist);
    scan1_kernel<<<196, 256, 0, stream>>>(hist, rowptr, bsum);
    scan2_kernel<<<1, 256, 0, stream>>>(bsum, boff);
    scan3_kernel<<<196, 256, 0, stream>>>(rowptr, boff, off);
    scatter_kernel<<<eb, 256, 0, stream>>>(ei, off, src_csr);

    const int gb = (N_NODES + 63) / 64;   // 782
    // layer 1: fused L+R linear (X read once), then fused node kernel
    lin1_fused_kernel<<<gb, 256, 0, stream>>>((const u16*)x, wt1, bl1, br1, xl1, xr1, N_NODES, cnt);
    const int nb = (N_NODES * 64 + 255) / 256;
    node1_kernel<<<nb, 256, 0, stream>>>(xl1, xr1, rowptr, hist, src_csr, att1, bias1, hbuf);

    // layer 2
    lin2_fused_kernel<<<gb, 256, 0, stream>>>(hbuf, wt2, bl2, br2, xl2, xr2, N_NODES);
    node2_kernel<<<nb, 256, 0, stream>>>(xl2, xr2, rowptr, hist, src_csr, att2, bias2, d_out, cnt);
}

// Round 7
// 276.976 us; speedup vs baseline: 8.1863x; 1.1200x over previous
//
#include <hip/hip_runtime.h>
#include <hip/hip_bf16.h>

typedef unsigned short u16;
typedef __attribute__((ext_vector_type(8))) short short8;
typedef __attribute__((ext_vector_type(4))) float floatx4;

#define N_NODES 50000
#define N_EDGES 400000
#define ET      450000   // edges + self loops
#define F_IN    128
#define C1      256      // H*HID
#define HID     64
#define OUTC    64
#define SLOPE   0.2f

__device__ __forceinline__ float bf2f(u16 v) {
    return __uint_as_float(((unsigned)v) << 16);
}
__device__ __forceinline__ u16 f2bf(float f) {   // round-to-nearest-even
    unsigned u = __float_as_uint(f);
    return (u16)((u + 0x7fffu + ((u >> 16) & 1u)) >> 16);
}

// ---------------- dtype detector (f32 vs bf16 input buffers) ----------------
__global__ __launch_bounds__(256) void detect_kernel(const unsigned* __restrict__ xw,
                                                     int* __restrict__ cnt)
{
    unsigned w = xw[threadIdx.x];
    unsigned aexp = (w >> 7) & 0xFFu;   // exponent field of low-half bf16
    if (aexp >= 170u || aexp <= 40u) atomicAdd(cnt, 1);
}

// ---------------- fused param convert --------------------------------------
__global__ __launch_bounds__(256) void convert_all_kernel(
    const void* wl1, const void* wr1, const void* wl2, const void* wr2,
    const void* s0, const void* s1, const void* s2, const void* s3,
    const void* s4, const void* s5, const void* s6, const void* s7,
    u16* __restrict__ wt, u16* __restrict__ prm, const int* __restrict__ cnt)
{
    bool f32m = (*cnt >= 32);
    if (blockIdx.x == 384) {
        for (int t = threadIdx.x; t < 1280; t += 256) {
            const void* src; int local;
            if      (t < 256)  { src = s0; local = t; }
            else if (t < 512)  { src = s1; local = t - 256; }
            else if (t < 768)  { src = s2; local = t - 512; }
            else if (t < 1024) { src = s3; local = t - 768; }
            else if (t < 1088) { src = s4; local = t - 1024; }
            else if (t < 1152) { src = s5; local = t - 1088; }
            else if (t < 1216) { src = s6; local = t - 1152; }
            else               { src = s7; local = t - 1216; }
            prm[t] = f32m ? f2bf(((const float*)src)[local]) : ((const u16*)src)[local];
        }
        return;
    }
    int t = blockIdx.x * 256 + threadIdx.x;   // 98304 total
    const void* src; int local, k, n, K, base;
    if (t < 32768)      { src = wl1; local = t;         k = local >> 8; n = local & 255; K = 128; base = 0; }
    else if (t < 65536) { src = wr1; local = t - 32768; k = local >> 8; n = local & 255; K = 128; base = 32768; }
    else if (t < 81920) { src = wl2; local = t - 65536; k = local >> 6; n = local & 63;  K = 256; base = 65536; }
    else                { src = wr2; local = t - 81920; k = local >> 6; n = local & 63;  K = 256; base = 81920; }
    u16 v = f32m ? f2bf(((const float*)src)[local]) : ((const u16*)src)[local];
    wt[base + n * K + k] = v;
}

// ---------------- CSR build (by dst) ----------------
__global__ __launch_bounds__(256) void hist_kernel(const int* __restrict__ ei,
                                                   int* __restrict__ hist)
{
    int t = blockIdx.x * 256 + threadIdx.x;
    if (t >= ET) return;
    int d = (t < N_EDGES) ? ei[N_EDGES + t] : t - N_EDGES;
    atomicAdd(&hist[d], 1);
}

__global__ __launch_bounds__(256) void scan1_kernel(const int* __restrict__ hist,
                                                    int* __restrict__ rowptr,
                                                    int* __restrict__ bsum)
{
    int t = threadIdx.x;
    int i = blockIdx.x * 256 + t;
    int v = (i < N_NODES) ? hist[i] : 0;
    __shared__ int sd[256];
    sd[t] = v;
    __syncthreads();
    #pragma unroll
    for (int ofs = 1; ofs < 256; ofs <<= 1) {
        int u = (t >= ofs) ? sd[t - ofs] : 0;
        __syncthreads();
        sd[t] += u;
        __syncthreads();
    }
    if (i < N_NODES) rowptr[i] = sd[t] - v;
    if (t == 255) bsum[blockIdx.x] = sd[255];
}

__global__ __launch_bounds__(256) void scan2_kernel(int* __restrict__ bsum,
                                                    int* __restrict__ boff)
{
    int t = threadIdx.x;
    int v = (t < 196) ? bsum[t] : 0;
    __shared__ int sd[256];
    sd[t] = v;
    __syncthreads();
    #pragma unroll
    for (int ofs = 1; ofs < 256; ofs <<= 1) {
        int u = (t >= ofs) ? sd[t - ofs] : 0;
        __syncthreads();
        sd[t] += u;
        __syncthreads();
    }
    if (t < 196) boff[t] = sd[t] - v;
}

__global__ __launch_bounds__(256) void scan3_kernel(int* __restrict__ rowptr,
                                                    const int* __restrict__ boff,
                                                    int* __restrict__ off)
{
    int i = blockIdx.x * 256 + threadIdx.x;
    if (i >= N_NODES) return;
    int r = rowptr[i] + boff[blockIdx.x];
    rowptr[i] = r;
    off[i] = r;
}

__global__ __launch_bounds__(256) void scatter_kernel(const int* __restrict__ ei,
                                                      int* __restrict__ off,
                                                      int* __restrict__ src_csr)
{
    int t = blockIdx.x * 256 + threadIdx.x;
    if (t >= ET) return;
    int s, d;
    if (t < N_EDGES) { s = ei[t]; d = ei[N_EDGES + t]; } else { s = d = t - N_EDGES; }
    int pos = atomicAdd(&off[d], 1);
    src_csr[pos] = s;
}

// ---------------- fused layer-1 linear: xl1 AND xr1 from one X staging ------
__global__ __launch_bounds__(256) void lin1_fused_kernel(
    const u16* __restrict__ X, const u16* __restrict__ Wt,   // Wt: [2][256][128]
    const u16* __restrict__ bl, const u16* __restrict__ br,
    u16* __restrict__ Yl, u16* __restrict__ Yr, int nrows,
    const int* __restrict__ cnt)
{
    constexpr int K = 128, N = 256, LS = K + 8;
    __shared__ __align__(16) u16 sX[64 * LS];
    __shared__ __align__(16) u16 sW[64 * LS];
    const bool f32m = (*cnt >= 32);
    const float* X32 = (const float*)X;
    const int row0 = blockIdx.x * 64;
    const int wave = threadIdx.x >> 6, lane = threadIdx.x & 63;
    const int quad = lane >> 4, l16 = lane & 15;

    for (int i = threadIdx.x * 8; i < 64 * K; i += 2048) {
        int r = i >> 7, c = i & 127;
        int gr = row0 + r;
        u16* dst = &sX[r * LS + c];
        if (f32m) {
            float4 v0 = make_float4(0.f, 0.f, 0.f, 0.f), v1 = v0;
            if (gr < nrows) {
                v0 = *(const float4*)&X32[(size_t)gr * K + c];
                v1 = *(const float4*)&X32[(size_t)gr * K + c + 4];
            }
            ushort4 p0, p1;
            p0.x = f2bf(v0.x); p0.y = f2bf(v0.y); p0.z = f2bf(v0.z); p0.w = f2bf(v0.w);
            p1.x = f2bf(v1.x); p1.y = f2bf(v1.y); p1.z = f2bf(v1.z); p1.w = f2bf(v1.w);
            *(ushort4*)dst = p0;
            *(ushort4*)(dst + 4) = p1;
        } else {
            uint4 v = {0u, 0u, 0u, 0u};
            if (gr < nrows) v = *(const uint4*)&X[(size_t)gr * K + c];
            *(uint4*)dst = v;
        }
    }

    for (int side = 0; side < 2; ++side) {
        const u16* wbase = Wt + side * (N * K);
        const u16* bias  = side ? br : bl;
        u16* Y = side ? Yr : Yl;
        for (int ch = 0; ch < 4; ++ch) {
            __syncthreads();
            for (int i = threadIdx.x * 8; i < 64 * K; i += 2048) {
                int n = i >> 7, c = i & 127;
                *(uint4*)&sW[n * LS + c] = *(const uint4*)&wbase[(size_t)(ch * 64 + n) * K + c];
            }
            __syncthreads();
            floatx4 acc0 = {0.f, 0.f, 0.f, 0.f}, acc1 = acc0, acc2 = acc0, acc3 = acc0;
            #pragma unroll
            for (int kk = 0; kk < 4; ++kk) {
                short8 a  = *(const short8*)&sX[(wave * 16 + l16) * LS + kk * 32 + quad * 8];
                short8 b0 = *(const short8*)&sW[(l16) * LS + kk * 32 + quad * 8];
                short8 b1 = *(const short8*)&sW[(16 + l16) * LS + kk * 32 + quad * 8];
                short8 b2 = *(const short8*)&sW[(32 + l16) * LS + kk * 32 + quad * 8];
                short8 b3 = *(const short8*)&sW[(48 + l16) * LS + kk * 32 + quad * 8];
                acc0 = __builtin_amdgcn_mfma_f32_16x16x32_bf16(a, b0, acc0, 0, 0, 0);
                acc1 = __builtin_amdgcn_mfma_f32_16x16x32_bf16(a, b1, acc1, 0, 0, 0);
                acc2 = __builtin_amdgcn_mfma_f32_16x16x32_bf16(a, b2, acc2, 0, 0, 0);
                acc3 = __builtin_amdgcn_mfma_f32_16x16x32_bf16(a, b3, acc3, 0, 0, 0);
            }
            const int rbase = row0 + wave * 16 + quad * 4;
            #pragma unroll
            for (int cf = 0; cf < 4; ++cf) {
                const floatx4 av = (cf == 0) ? acc0 : (cf == 1) ? acc1 : (cf == 2) ? acc2 : acc3;
                const int col = ch * 64 + cf * 16 + l16;
                const float bv = bf2f(bias[col]);
                #pragma unroll
                for (int r = 0; r < 4; ++r) {
                    int row = rbase + r;
                    if (row < nrows) Y[(size_t)row * N + col] = f2bf(av[r] + bv);
                }
            }
        }
    }
}

// ---------------- fused layer-2 linear ------------------------------------
__global__ __launch_bounds__(256) void lin2_fused_kernel(
    const u16* __restrict__ X, const u16* __restrict__ Wt,   // Wt: [2][64][256]
    const u16* __restrict__ bl, const u16* __restrict__ br,
    u16* __restrict__ Yl, u16* __restrict__ Yr, int nrows)
{
    constexpr int K = 256, N = 64, LS = K + 8;
    __shared__ __align__(16) u16 sX[64 * LS];
    __shared__ __align__(16) u16 sW[64 * LS];
    const int row0 = blockIdx.x * 64;
    const int wave = threadIdx.x >> 6, lane = threadIdx.x & 63;
    const int quad = lane >> 4, l16 = lane & 15;

    for (int i = threadIdx.x * 8; i < 64 * K; i += 2048) {
        int r = i >> 8, c = i & 255;
        int gr = row0 + r;
        uint4 v = {0u, 0u, 0u, 0u};
        if (gr < nrows) v = *(const uint4*)&X[(size_t)gr * K + c];
        *(uint4*)&sX[r * LS + c] = v;
    }

    for (int side = 0; side < 2; ++side) {
        const u16* wbase = Wt + side * (N * K);
        const u16* bias  = side ? br : bl;
        u16* Y = side ? Yr : Yl;
        __syncthreads();
        for (int i = threadIdx.x * 8; i < 64 * K; i += 2048) {
            int n = i >> 8, c = i & 255;
            *(uint4*)&sW[n * LS + c] = *(const uint4*)&wbase[(size_t)n * K + c];
        }
        __syncthreads();
        floatx4 acc0 = {0.f, 0.f, 0.f, 0.f}, acc1 = acc0, acc2 = acc0, acc3 = acc0;
        #pragma unroll
        for (int kk = 0; kk < 8; ++kk) {
            short8 a  = *(const short8*)&sX[(wave * 16 + l16) * LS + kk * 32 + quad * 8];
            short8 b0 = *(const short8*)&sW[(l16) * LS + kk * 32 + quad * 8];
            short8 b1 = *(const short8*)&sW[(16 + l16) * LS + kk * 32 + quad * 8];
            short8 b2 = *(const short8*)&sW[(32 + l16) * LS + kk * 32 + quad * 8];
            short8 b3 = *(const short8*)&sW[(48 + l16) * LS + kk * 32 + quad * 8];
            acc0 = __builtin_amdgcn_mfma_f32_16x16x32_bf16(a, b0, acc0, 0, 0, 0);
            acc1 = __builtin_amdgcn_mfma_f32_16x16x32_bf16(a, b1, acc1, 0, 0, 0);
            acc2 = __builtin_amdgcn_mfma_f32_16x16x32_bf16(a, b2, acc2, 0, 0, 0);
            acc3 = __builtin_amdgcn_mfma_f32_16x16x32_bf16(a, b3, acc3, 0, 0, 0);
        }
        const int rbase = row0 + wave * 16 + quad * 4;
        #pragma unroll
        for (int cf = 0; cf < 4; ++cf) {
            const floatx4 av = (cf == 0) ? acc0 : (cf == 1) ? acc1 : (cf == 2) ? acc2 : acc3;
            const int col = cf * 16 + l16;
            const float bv = bf2f(bias[col]);
            #pragma unroll
            for (int r = 0; r < 4; ++r) {
                int row = rbase + r;
                if (row < nrows) Y[(size_t)row * N + col] = f2bf(av[r] + bv);
            }
        }
    }
}

// ---------------- layer 1 fused per-node GATv2 (4 heads x 64 ch) ------------
// one wave per node; lane l: head h=l>>4, channels [4l, 4l+4)
// 4 edges per iteration (ILP-4 shuffle chains), masked tail, single rescale.
__global__ __launch_bounds__(256) void node1_kernel(
    const u16* __restrict__ xl, const u16* __restrict__ xr,
    const int* __restrict__ rowptr, const int* __restrict__ hist,
    const int* __restrict__ src_csr, const u16* __restrict__ att,
    const u16* __restrict__ bias, u16* __restrict__ hout)
{
    int gid = blockIdx.x * 256 + threadIdx.x;
    int d = gid >> 6, l = gid & 63;
    if (d >= N_NODES) return;
    const int start = rowptr[d];
    const int deg = hist[d];

    ushort4 av = *(const ushort4*)&att[l * 4];
    const float at0 = bf2f(av.x), at1 = bf2f(av.y), at2 = bf2f(av.z), at3 = bf2f(av.w);
    ushort4 xrv = *(const ushort4*)&xr[(size_t)d * C1 + l * 4];
    const float r0 = bf2f(xrv.x), r1 = bf2f(xrv.y), r2 = bf2f(xrv.z), r3 = bf2f(xrv.w);

    float m = -1e30f, la = 0.f;
    float a0 = 0.f, a1 = 0.f, a2 = 0.f, a3 = 0.f;
    for (int j = 0; j < deg; j += 4) {
        const bool v1 = j + 1 < deg, v2 = j + 2 < deg, v3 = j + 3 < deg;
        int s0 = src_csr[start + j];
        int s1 = v1 ? src_csr[start + j + 1] : s0;
        int s2 = v2 ? src_csr[start + j + 2] : s0;
        int s3 = v3 ? src_csr[start + j + 3] : s0;
        ushort4 u0 = *(const ushort4*)&xl[(size_t)s0 * C1 + l * 4];
        ushort4 u1 = *(const ushort4*)&xl[(size_t)s1 * C1 + l * 4];
        ushort4 u2 = *(const ushort4*)&xl[(size_t)s2 * C1 + l * 4];
        ushort4 u3 = *(const ushort4*)&xl[(size_t)s3 * C1 + l * 4];
        float x00 = bf2f(u0.x), x01 = bf2f(u0.y), x02 = bf2f(u0.z), x03 = bf2f(u0.w);
        float x10 = bf2f(u1.x), x11 = bf2f(u1.y), x12 = bf2f(u1.z), x13 = bf2f(u1.w);
        float x20 = bf2f(u2.x), x21 = bf2f(u2.y), x22 = bf2f(u2.z), x23 = bf2f(u2.w);
        float x30 = bf2f(u3.x), x31 = bf2f(u3.y), x32 = bf2f(u3.z), x33 = bf2f(u3.w);
        float t, p0 = 0.f, p1 = 0.f, p2 = 0.f, p3 = 0.f;
        t = x00 + r0; t = t > 0.f ? t : SLOPE * t; p0 += t * at0;
        t = x01 + r1; t = t > 0.f ? t : SLOPE * t; p0 += t * at1;
        t = x02 + r2; t = t > 0.f ? t : SLOPE * t; p0 += t * at2;
        t = x03 + r3; t = t > 0.f ? t : SLOPE * t; p0 += t * at3;
        t = x10 + r0; t = t > 0.f ? t : SLOPE * t; p1 += t * at0;
        t = x11 + r1; t = t > 0.f ? t : SLOPE * t; p1 += t * at1;
        t = x12 + r2; t = t > 0.f ? t : SLOPE * t; p1 += t * at2;
        t = x13 + r3; t = t > 0.f ? t : SLOPE * t; p1 += t * at3;
        t = x20 + r0; t = t > 0.f ? t : SLOPE * t; p2 += t * at0;
        t = x21 + r1; t = t > 0.f ? t : SLOPE * t; p2 += t * at1;
        t = x22 + r2; t = t > 0.f ? t : SLOPE * t; p2 += t * at2;
        t = x23 + r3; t = t > 0.f ? t : SLOPE * t; p2 += t * at3;
        t = x30 + r0; t = t > 0.f ? t : SLOPE * t; p3 += t * at0;
        t = x31 + r1; t = t > 0.f ? t : SLOPE * t; p3 += t * at1;
        t = x32 + r2; t = t > 0.f ? t : SLOPE * t; p3 += t * at2;
        t = x33 + r3; t = t > 0.f ? t : SLOPE * t; p3 += t * at3;
        p0 += __shfl_xor(p0, 1); p1 += __shfl_xor(p1, 1); p2 += __shfl_xor(p2, 1); p3 += __shfl_xor(p3, 1);
        p0 += __shfl_xor(p0, 2); p1 += __shfl_xor(p1, 2); p2 += __shfl_xor(p2, 2); p3 += __shfl_xor(p3, 2);
        p0 += __shfl_xor(p0, 4); p1 += __shfl_xor(p1, 4); p2 += __shfl_xor(p2, 4); p3 += __shfl_xor(p3, 4);
        p0 += __shfl_xor(p0, 8); p1 += __shfl_xor(p1, 8); p2 += __shfl_xor(p2, 8); p3 += __shfl_xor(p3, 8);
        float pm = p0;
        if (v1) pm = fmaxf(pm, p1);
        if (v2) pm = fmaxf(pm, p2);
        if (v3) pm = fmaxf(pm, p3);
        float mn = fmaxf(m, pm);
        float sc = __expf(m - mn);
        float w0 = __expf(p0 - mn);
        float w1 = v1 ? __expf(p1 - mn) : 0.f;
        float w2 = v2 ? __expf(p2 - mn) : 0.f;
        float w3 = v3 ? __expf(p3 - mn) : 0.f;
        la = la * sc + w0 + w1 + w2 + w3;
        a0 = a0 * sc + w0 * x00 + w1 * x10 + w2 * x20 + w3 * x30;
        a1 = a1 * sc + w0 * x01 + w1 * x11 + w2 * x21 + w3 * x31;
        a2 = a2 * sc + w0 * x02 + w1 * x12 + w2 * x22 + w3 * x32;
        a3 = a3 * sc + w0 * x03 + w1 * x13 + w2 * x23 + w3 * x33;
        m = mn;
    }
    const float inv = 1.f / la;
    const int c = l * 4;
    float v0 = a0 * inv + bf2f(bias[c + 0]);
    float v1 = a1 * inv + bf2f(bias[c + 1]);
    float v2 = a2 * inv + bf2f(bias[c + 2]);
    float v3 = a3 * inv + bf2f(bias[c + 3]);
    v0 = v0 > 0.f ? v0 : __expf(fminf(v0, 0.f)) - 1.f;
    v1 = v1 > 0.f ? v1 : __expf(fminf(v1, 0.f)) - 1.f;
    v2 = v2 > 0.f ? v2 : __expf(fminf(v2, 0.f)) - 1.f;
    v3 = v3 > 0.f ? v3 : __expf(fminf(v3, 0.f)) - 1.f;
    ushort4 o;
    o.x = f2bf(v0); o.y = f2bf(v1); o.z = f2bf(v2); o.w = f2bf(v3);
    *(ushort4*)&hout[(size_t)d * C1 + c] = o;
}

// ---------------- layer 2 fused per-node GATv2 (1 head x 64 ch) --------------
// one wave per node, split into 4x 16-lane groups; group g handles edge j+g,
// lane sub covers channels [4*sub, 4*sub+4). Score reduce: 4 shuffle stages
// shared by all 4 edges. Cross-group online-softmax merge at the end.
__global__ __launch_bounds__(256) void node2_kernel(
    const u16* __restrict__ xl, const u16* __restrict__ xr,
    const int* __restrict__ rowptr, const int* __restrict__ hist,
    const int* __restrict__ src_csr, const u16* __restrict__ att,
    const u16* __restrict__ bias, void* __restrict__ outp,
    const int* __restrict__ cnt)
{
    int gid = blockIdx.x * 256 + threadIdx.x;
    int d = gid >> 6, l = gid & 63;
    if (d >= N_NODES) return;
    const int start = rowptr[d];
    const int deg = hist[d];
    const int g = l >> 4, sub = l & 15;
    const int c0 = sub * 4;

    ushort4 av = *(const ushort4*)&att[c0];
    const float at0 = bf2f(av.x), at1 = bf2f(av.y), at2 = bf2f(av.z), at3 = bf2f(av.w);
    ushort4 rv = *(const ushort4*)&xr[(size_t)d * OUTC + c0];
    const float r0 = bf2f(rv.x), r1 = bf2f(rv.y), r2 = bf2f(rv.z), r3 = bf2f(rv.w);

    float m = -1e30f, la = 0.f;
    float a0 = 0.f, a1 = 0.f, a2 = 0.f, a3 = 0.f;
    for (int j = 0; j < deg; j += 4) {
        const int jj = j + g;
        const bool valid = jj < deg;
        int s = valid ? src_csr[start + jj] : d;
        ushort4 xv = *(const ushort4*)&xl[(size_t)s * OUTC + c0];
        float x0 = bf2f(xv.x), x1 = bf2f(xv.y), x2 = bf2f(xv.z), x3 = bf2f(xv.w);
        float t, p = 0.f;
        t = x0 + r0; t = t > 0.f ? t : SLOPE * t; p += t * at0;
        t = x1 + r1; t = t > 0.f ? t : SLOPE * t; p += t * at1;
        t = x2 + r2; t = t > 0.f ? t : SLOPE * t; p += t * at2;
        t = x3 + r3; t = t > 0.f ? t : SLOPE * t; p += t * at3;
        p += __shfl_xor(p, 1);   // group-local: xor of bits 0..3 stays in group
        p += __shfl_xor(p, 2);
        p += __shfl_xor(p, 4);
        p += __shfl_xor(p, 8);
        float pv = valid ? p : -1e30f;
        float mn = fmaxf(m, pv);
        float sc = __expf(m - mn);
        float w  = valid ? __expf(p - mn) : 0.f;
        la = la * sc + w;
        a0 = a0 * sc + w * x0;
        a1 = a1 * sc + w * x1;
        a2 = a2 * sc + w * x2;
        a3 = a3 * sc + w * x3;
        m = mn;
    }
    // merge the 4 groups' online-softmax states (xor 16, then 32)
    #pragma unroll
    for (int ofs = 16; ofs <= 32; ofs <<= 1) {
        float mo = __shfl_xor(m, ofs);
        float lo = __shfl_xor(la, ofs);
        float b0 = __shfl_xor(a0, ofs);
        float b1 = __shfl_xor(a1, ofs);
        float b2 = __shfl_xor(a2, ofs);
        float b3 = __shfl_xor(a3, ofs);
        float mn = fmaxf(m, mo);
        float s0 = __expf(m - mn), s1 = __expf(mo - mn);
        la = la * s0 + lo * s1;
        a0 = a0 * s0 + b0 * s1;
        a1 = a1 * s0 + b1 * s1;
        a2 = a2 * s0 + b2 * s1;
        a3 = a3 * s0 + b3 * s1;
        m = mn;
    }
    if (g == 0) {
        const float inv = 1.f / la;
        float v0 = a0 * inv + bf2f(bias[c0 + 0]);
        float v1 = a1 * inv + bf2f(bias[c0 + 1]);
        float v2 = a2 * inv + bf2f(bias[c0 + 2]);
        float v3 = a3 * inv + bf2f(bias[c0 + 3]);
        if (*cnt >= 32) {
            float4 o = make_float4(v0, v1, v2, v3);
            *(float4*)&((float*)outp)[(size_t)d * OUTC + c0] = o;
        } else {
            ushort4 o;
            o.x = f2bf(v0); o.y = f2bf(v1); o.z = f2bf(v2); o.w = f2bf(v3);
            *(ushort4*)&((u16*)outp)[(size_t)d * OUTC + c0] = o;
        }
    }
}

extern "C" void kernel_launch(void* const* d_in, const int* in_sizes, int n_in,
                              void* d_out, int out_size, void* d_ws, size_t ws_size,
                              hipStream_t stream)
{
    const void* x  = d_in[0];
    const int*  ei = (const int*)d_in[1];

    char* ws = (char*)d_ws;
    u16* xl1     = (u16*)(ws + 0);          // 25.6 MB
    u16* xr1     = (u16*)(ws + 25600000);   // 25.6 MB
    u16* hbuf    = (u16*)(ws + 51200000);   // 25.6 MB
    u16* xl2     = (u16*)(ws + 0);          // overlay xl1 (dead after node1)
    u16* xr2     = (u16*)(ws + 6400000);
    int* hist    = (int*)(ws + 76800000);
    int* rowptr  = (int*)(ws + 77000000);
    int* off     = (int*)(ws + 77200000);
    int* src_csr = (int*)(ws + 77400000);   // 1.8 MB
    int* cnt     = (int*)(ws + 79200000);
    u16* prm     = (u16*)(ws + 79200064);   // 1280 u16 small params
    u16* wt      = (u16*)(ws + 79210240);   // 98304 u16 transposed weights
    int* bsum    = (int*)(ws + 79410000);
    int* boff    = (int*)(ws + 79411024);

    u16* bl1   = prm + 0;
    u16* br1   = prm + 256;
    u16* att1  = prm + 512;
    u16* bias1 = prm + 768;
    u16* bl2   = prm + 1024;
    u16* br2   = prm + 1088;
    u16* att2  = prm + 1152;
    u16* bias2 = prm + 1216;
    u16* wt1   = wt + 0;       // [2][256][128]
    u16* wt2   = wt + 65536;   // [2][64][256]

    hipMemsetAsync(cnt, 0, 4, stream);
    detect_kernel<<<1, 256, 0, stream>>>((const unsigned*)x, cnt);
    convert_all_kernel<<<385, 256, 0, stream>>>(
        d_in[2], d_in[4], d_in[8], d_in[10],
        d_in[3], d_in[5], d_in[6], d_in[7], d_in[9], d_in[11], d_in[12], d_in[13],
        wt, prm, cnt);

    hipMemsetAsync(hist, 0, 200000, stream);
    const int eb = (ET + 255) / 256;
    hist_kernel<<<eb, 256, 0, stream>>>(ei, hist);
    scan1_kernel<<<196, 256, 0, stream>>>(hist, rowptr, bsum);
    scan2_kernel<<<1, 256, 0, stream>>>(bsum, boff);
    scan3_kernel<<<196, 256, 0, stream>>>(rowptr, boff, off);
    scatter_kernel<<<eb, 256, 0, stream>>>(ei, off, src_csr);

    const int gb = (N_NODES + 63) / 64;   // 782
    lin1_fused_kernel<<<gb, 256, 0, stream>>>((const u16*)x, wt1, bl1, br1, xl1, xr1, N_NODES, cnt);
    const int nb = (N_NODES * 64 + 255) / 256;
    node1_kernel<<<nb, 256, 0, stream>>>(xl1, xr1, rowptr, hist, src_csr, att1, bias1, hbuf);

    lin2_fused_kernel<<<gb, 256, 0, stream>>>(hbuf, wt2, bl2, br2, xl2, xr2, N_NODES);
    node2_kernel<<<nb, 256, 0, stream>>>(xl2, xr2, rowptr, hist, src_csr, att2, bias2, d_out, cnt);
}

// Round 8
// 270.697 us; speedup vs baseline: 8.3762x; 1.0232x over previous
//
#include <hip/hip_runtime.h>
#include <hip/hip_bf16.h>

typedef unsigned short u16;
typedef __attribute__((ext_vector_type(8))) short short8;
typedef __attribute__((ext_vector_type(4))) float floatx4;

#define N_NODES 50000
#define N_EDGES 400000
#define ET      450000   // edges + self loops
#define F_IN    128
#define C1      256      // H*HID
#define HID     64
#define OUTC    64
#define SLOPE   0.2f

__device__ __forceinline__ float bf2f(u16 v) {
    return __uint_as_float(((unsigned)v) << 16);
}
__device__ __forceinline__ u16 f2bf(float f) {   // round-to-nearest-even
    unsigned u = __float_as_uint(f);
    return (u16)((u + 0x7fffu + ((u >> 16) & 1u)) >> 16);
}

// ---------------- dtype detector (f32 vs bf16 input buffers) ----------------
__global__ __launch_bounds__(256) void detect_kernel(const unsigned* __restrict__ xw,
                                                     int* __restrict__ cnt)
{
    unsigned w = xw[threadIdx.x];
    unsigned aexp = (w >> 7) & 0xFFu;   // exponent field of low-half bf16
    if (aexp >= 170u || aexp <= 40u) atomicAdd(cnt, 1);
}

// ---------------- fused param convert --------------------------------------
__global__ __launch_bounds__(256) void convert_all_kernel(
    const void* wl1, const void* wr1, const void* wl2, const void* wr2,
    const void* s0, const void* s1, const void* s2, const void* s3,
    const void* s4, const void* s5, const void* s6, const void* s7,
    u16* __restrict__ wt, u16* __restrict__ prm, const int* __restrict__ cnt)
{
    bool f32m = (*cnt >= 32);
    if (blockIdx.x == 384) {
        for (int t = threadIdx.x; t < 1280; t += 256) {
            const void* src; int local;
            if      (t < 256)  { src = s0; local = t; }
            else if (t < 512)  { src = s1; local = t - 256; }
            else if (t < 768)  { src = s2; local = t - 512; }
            else if (t < 1024) { src = s3; local = t - 768; }
            else if (t < 1088) { src = s4; local = t - 1024; }
            else if (t < 1152) { src = s5; local = t - 1088; }
            else if (t < 1216) { src = s6; local = t - 1152; }
            else               { src = s7; local = t - 1216; }
            prm[t] = f32m ? f2bf(((const float*)src)[local]) : ((const u16*)src)[local];
        }
        return;
    }
    int t = blockIdx.x * 256 + threadIdx.x;   // 98304 total
    const void* src; int local, k, n, K, base;
    if (t < 32768)      { src = wl1; local = t;         k = local >> 8; n = local & 255; K = 128; base = 0; }
    else if (t < 65536) { src = wr1; local = t - 32768; k = local >> 8; n = local & 255; K = 128; base = 32768; }
    else if (t < 81920) { src = wl2; local = t - 65536; k = local >> 6; n = local & 63;  K = 256; base = 65536; }
    else                { src = wr2; local = t - 81920; k = local >> 6; n = local & 63;  K = 256; base = 81920; }
    u16 v = f32m ? f2bf(((const float*)src)[local]) : ((const u16*)src)[local];
    wt[base + n * K + k] = v;
}

// ---------------- CSR build (by dst) ----------------
__global__ __launch_bounds__(256) void hist_kernel(const int* __restrict__ ei,
                                                   int* __restrict__ hist)
{
    int t = blockIdx.x * 256 + threadIdx.x;
    if (t >= ET) return;
    int d = (t < N_EDGES) ? ei[N_EDGES + t] : t - N_EDGES;
    atomicAdd(&hist[d], 1);
}

__global__ __launch_bounds__(256) void scan1_kernel(const int* __restrict__ hist,
                                                    int* __restrict__ rowptr,
                                                    int* __restrict__ bsum)
{
    int t = threadIdx.x;
    int i = blockIdx.x * 256 + t;
    int v = (i < N_NODES) ? hist[i] : 0;
    __shared__ int sd[256];
    sd[t] = v;
    __syncthreads();
    #pragma unroll
    for (int ofs = 1; ofs < 256; ofs <<= 1) {
        int u = (t >= ofs) ? sd[t - ofs] : 0;
        __syncthreads();
        sd[t] += u;
        __syncthreads();
    }
    if (i < N_NODES) rowptr[i] = sd[t] - v;
    if (t == 255) bsum[blockIdx.x] = sd[255];
}

__global__ __launch_bounds__(256) void scan2_kernel(int* __restrict__ bsum,
                                                    int* __restrict__ boff)
{
    int t = threadIdx.x;
    int v = (t < 196) ? bsum[t] : 0;
    __shared__ int sd[256];
    sd[t] = v;
    __syncthreads();
    #pragma unroll
    for (int ofs = 1; ofs < 256; ofs <<= 1) {
        int u = (t >= ofs) ? sd[t - ofs] : 0;
        __syncthreads();
        sd[t] += u;
        __syncthreads();
    }
    if (t < 196) boff[t] = sd[t] - v;
}

__global__ __launch_bounds__(256) void scan3_kernel(int* __restrict__ rowptr,
                                                    const int* __restrict__ boff,
                                                    int* __restrict__ off)
{
    int i = blockIdx.x * 256 + threadIdx.x;
    if (i >= N_NODES) return;
    int r = rowptr[i] + boff[blockIdx.x];
    rowptr[i] = r;
    off[i] = r;
}

__global__ __launch_bounds__(256) void scatter_kernel(const int* __restrict__ ei,
                                                      int* __restrict__ off,
                                                      int* __restrict__ src_csr)
{
    int t = blockIdx.x * 256 + threadIdx.x;
    if (t >= ET) return;
    int s, d;
    if (t < N_EDGES) { s = ei[t]; d = ei[N_EDGES + t]; } else { s = d = t - N_EDGES; }
    int pos = atomicAdd(&off[d], 1);
    src_csr[pos] = s;
}

// ---------------- fused layer-1 linear: xl1 AND xr1 from one X staging ------
__global__ __launch_bounds__(256) void lin1_fused_kernel(
    const u16* __restrict__ X, const u16* __restrict__ Wt,   // Wt: [2][256][128]
    const u16* __restrict__ bl, const u16* __restrict__ br,
    u16* __restrict__ Yl, u16* __restrict__ Yr, int nrows,
    const int* __restrict__ cnt)
{
    constexpr int K = 128, N = 256, LS = K + 8;
    __shared__ __align__(16) u16 sX[64 * LS];
    __shared__ __align__(16) u16 sW[64 * LS];
    const bool f32m = (*cnt >= 32);
    const float* X32 = (const float*)X;
    const int row0 = blockIdx.x * 64;
    const int wave = threadIdx.x >> 6, lane = threadIdx.x & 63;
    const int quad = lane >> 4, l16 = lane & 15;

    for (int i = threadIdx.x * 8; i < 64 * K; i += 2048) {
        int r = i >> 7, c = i & 127;
        int gr = row0 + r;
        u16* dst = &sX[r * LS + c];
        if (f32m) {
            float4 v0 = make_float4(0.f, 0.f, 0.f, 0.f), v1 = v0;
            if (gr < nrows) {
                v0 = *(const float4*)&X32[(size_t)gr * K + c];
                v1 = *(const float4*)&X32[(size_t)gr * K + c + 4];
            }
            ushort4 p0, p1;
            p0.x = f2bf(v0.x); p0.y = f2bf(v0.y); p0.z = f2bf(v0.z); p0.w = f2bf(v0.w);
            p1.x = f2bf(v1.x); p1.y = f2bf(v1.y); p1.z = f2bf(v1.z); p1.w = f2bf(v1.w);
            *(ushort4*)dst = p0;
            *(ushort4*)(dst + 4) = p1;
        } else {
            uint4 v = {0u, 0u, 0u, 0u};
            if (gr < nrows) v = *(const uint4*)&X[(size_t)gr * K + c];
            *(uint4*)dst = v;
        }
    }

    for (int side = 0; side < 2; ++side) {
        const u16* wbase = Wt + side * (N * K);
        const u16* bias  = side ? br : bl;
        u16* Y = side ? Yr : Yl;
        for (int ch = 0; ch < 4; ++ch) {
            __syncthreads();
            for (int i = threadIdx.x * 8; i < 64 * K; i += 2048) {
                int n = i >> 7, c = i & 127;
                *(uint4*)&sW[n * LS + c] = *(const uint4*)&wbase[(size_t)(ch * 64 + n) * K + c];
            }
            __syncthreads();
            floatx4 acc0 = {0.f, 0.f, 0.f, 0.f}, acc1 = acc0, acc2 = acc0, acc3 = acc0;
            #pragma unroll
            for (int kk = 0; kk < 4; ++kk) {
                short8 a  = *(const short8*)&sX[(wave * 16 + l16) * LS + kk * 32 + quad * 8];
                short8 b0 = *(const short8*)&sW[(l16) * LS + kk * 32 + quad * 8];
                short8 b1 = *(const short8*)&sW[(16 + l16) * LS + kk * 32 + quad * 8];
                short8 b2 = *(const short8*)&sW[(32 + l16) * LS + kk * 32 + quad * 8];
                short8 b3 = *(const short8*)&sW[(48 + l16) * LS + kk * 32 + quad * 8];
                acc0 = __builtin_amdgcn_mfma_f32_16x16x32_bf16(a, b0, acc0, 0, 0, 0);
                acc1 = __builtin_amdgcn_mfma_f32_16x16x32_bf16(a, b1, acc1, 0, 0, 0);
                acc2 = __builtin_amdgcn_mfma_f32_16x16x32_bf16(a, b2, acc2, 0, 0, 0);
                acc3 = __builtin_amdgcn_mfma_f32_16x16x32_bf16(a, b3, acc3, 0, 0, 0);
            }
            const int rbase = row0 + wave * 16 + quad * 4;
            #pragma unroll
            for (int cf = 0; cf < 4; ++cf) {
                const floatx4 av = (cf == 0) ? acc0 : (cf == 1) ? acc1 : (cf == 2) ? acc2 : acc3;
                const int col = ch * 64 + cf * 16 + l16;
                const float bv = bf2f(bias[col]);
                #pragma unroll
                for (int r = 0; r < 4; ++r) {
                    int row = rbase + r;
                    if (row < nrows) Y[(size_t)row * N + col] = f2bf(av[r] + bv);
                }
            }
        }
    }
}

// ---------------- fused layer-2 linear ------------------------------------
__global__ __launch_bounds__(256) void lin2_fused_kernel(
    const u16* __restrict__ X, const u16* __restrict__ Wt,   // Wt: [2][64][256]
    const u16* __restrict__ bl, const u16* __restrict__ br,
    u16* __restrict__ Yl, u16* __restrict__ Yr, int nrows)
{
    constexpr int K = 256, N = 64, LS = K + 8;
    __shared__ __align__(16) u16 sX[64 * LS];
    __shared__ __align__(16) u16 sW[64 * LS];
    const int row0 = blockIdx.x * 64;
    const int wave = threadIdx.x >> 6, lane = threadIdx.x & 63;
    const int quad = lane >> 4, l16 = lane & 15;

    for (int i = threadIdx.x * 8; i < 64 * K; i += 2048) {
        int r = i >> 8, c = i & 255;
        int gr = row0 + r;
        uint4 v = {0u, 0u, 0u, 0u};
        if (gr < nrows) v = *(const uint4*)&X[(size_t)gr * K + c];
        *(uint4*)&sX[r * LS + c] = v;
    }

    for (int side = 0; side < 2; ++side) {
        const u16* wbase = Wt + side * (N * K);
        const u16* bias  = side ? br : bl;
        u16* Y = side ? Yr : Yl;
        __syncthreads();
        for (int i = threadIdx.x * 8; i < 64 * K; i += 2048) {
            int n = i >> 8, c = i & 255;
            *(uint4*)&sW[n * LS + c] = *(const uint4*)&wbase[(size_t)n * K + c];
        }
        __syncthreads();
        floatx4 acc0 = {0.f, 0.f, 0.f, 0.f}, acc1 = acc0, acc2 = acc0, acc3 = acc0;
        #pragma unroll
        for (int kk = 0; kk < 8; ++kk) {
            short8 a  = *(const short8*)&sX[(wave * 16 + l16) * LS + kk * 32 + quad * 8];
            short8 b0 = *(const short8*)&sW[(l16) * LS + kk * 32 + quad * 8];
            short8 b1 = *(const short8*)&sW[(16 + l16) * LS + kk * 32 + quad * 8];
            short8 b2 = *(const short8*)&sW[(32 + l16) * LS + kk * 32 + quad * 8];
            short8 b3 = *(const short8*)&sW[(48 + l16) * LS + kk * 32 + quad * 8];
            acc0 = __builtin_amdgcn_mfma_f32_16x16x32_bf16(a, b0, acc0, 0, 0, 0);
            acc1 = __builtin_amdgcn_mfma_f32_16x16x32_bf16(a, b1, acc1, 0, 0, 0);
            acc2 = __builtin_amdgcn_mfma_f32_16x16x32_bf16(a, b2, acc2, 0, 0, 0);
            acc3 = __builtin_amdgcn_mfma_f32_16x16x32_bf16(a, b3, acc3, 0, 0, 0);
        }
        const int rbase = row0 + wave * 16 + quad * 4;
        #pragma unroll
        for (int cf = 0; cf < 4; ++cf) {
            const floatx4 av = (cf == 0) ? acc0 : (cf == 1) ? acc1 : (cf == 2) ? acc2 : acc3;
            const int col = cf * 16 + l16;
            const float bv = bf2f(bias[col]);
            #pragma unroll
            for (int r = 0; r < 4; ++r) {
                int row = rbase + r;
                if (row < nrows) Y[(size_t)row * N + col] = f2bf(av[r] + bv);
            }
        }
    }
}

// ---------------- layer 1 fused per-node GATv2 (4 heads x 64 ch) ------------
// one wave per node; d forced wave-uniform via readfirstlane so rowptr/hist/
// src_csr loads are scalar (s_load) and gather bases live in SGPRs.
__global__ __launch_bounds__(256) void node1_kernel(
    const u16* __restrict__ xl, const u16* __restrict__ xr,
    const int* __restrict__ rowptr, const int* __restrict__ hist,
    const int* __restrict__ src_csr, const u16* __restrict__ att,
    const u16* __restrict__ bias, u16* __restrict__ hout)
{
    const int d = __builtin_amdgcn_readfirstlane(blockIdx.x * 4 + (threadIdx.x >> 6));
    if (d >= N_NODES) return;
    const int l = threadIdx.x & 63;
    const int start = rowptr[d];
    const int deg = hist[d];

    ushort4 av = *(const ushort4*)&att[l * 4];
    const float at0 = bf2f(av.x), at1 = bf2f(av.y), at2 = bf2f(av.z), at3 = bf2f(av.w);
    ushort4 xrv = *(const ushort4*)&xr[(size_t)d * C1 + l * 4];
    const float r0 = bf2f(xrv.x), r1 = bf2f(xrv.y), r2 = bf2f(xrv.z), r3 = bf2f(xrv.w);

    float m = -1e30f, la = 0.f;
    float a0 = 0.f, a1 = 0.f, a2 = 0.f, a3 = 0.f;
    for (int j = 0; j < deg; j += 4) {
        const bool v1 = j + 1 < deg, v2 = j + 2 < deg, v3 = j + 3 < deg;
        int s0 = src_csr[start + j];
        int s1 = v1 ? src_csr[start + j + 1] : s0;
        int s2 = v2 ? src_csr[start + j + 2] : s0;
        int s3 = v3 ? src_csr[start + j + 3] : s0;
        ushort4 u0 = *(const ushort4*)&xl[(size_t)s0 * C1 + l * 4];
        ushort4 u1 = *(const ushort4*)&xl[(size_t)s1 * C1 + l * 4];
        ushort4 u2 = *(const ushort4*)&xl[(size_t)s2 * C1 + l * 4];
        ushort4 u3 = *(const ushort4*)&xl[(size_t)s3 * C1 + l * 4];
        float x00 = bf2f(u0.x), x01 = bf2f(u0.y), x02 = bf2f(u0.z), x03 = bf2f(u0.w);
        float x10 = bf2f(u1.x), x11 = bf2f(u1.y), x12 = bf2f(u1.z), x13 = bf2f(u1.w);
        float x20 = bf2f(u2.x), x21 = bf2f(u2.y), x22 = bf2f(u2.z), x23 = bf2f(u2.w);
        float x30 = bf2f(u3.x), x31 = bf2f(u3.y), x32 = bf2f(u3.z), x33 = bf2f(u3.w);
        float t, p0 = 0.f, p1 = 0.f, p2 = 0.f, p3 = 0.f;
        t = x00 + r0; t = t > 0.f ? t : SLOPE * t; p0 += t * at0;
        t = x01 + r1; t = t > 0.f ? t : SLOPE * t; p0 += t * at1;
        t = x02 + r2; t = t > 0.f ? t : SLOPE * t; p0 += t * at2;
        t = x03 + r3; t = t > 0.f ? t : SLOPE * t; p0 += t * at3;
        t = x10 + r0; t = t > 0.f ? t : SLOPE * t; p1 += t * at0;
        t = x11 + r1; t = t > 0.f ? t : SLOPE * t; p1 += t * at1;
        t = x12 + r2; t = t > 0.f ? t : SLOPE * t; p1 += t * at2;
        t = x13 + r3; t = t > 0.f ? t : SLOPE * t; p1 += t * at3;
        t = x20 + r0; t = t > 0.f ? t : SLOPE * t; p2 += t * at0;
        t = x21 + r1; t = t > 0.f ? t : SLOPE * t; p2 += t * at1;
        t = x22 + r2; t = t > 0.f ? t : SLOPE * t; p2 += t * at2;
        t = x23 + r3; t = t > 0.f ? t : SLOPE * t; p2 += t * at3;
        t = x30 + r0; t = t > 0.f ? t : SLOPE * t; p3 += t * at0;
        t = x31 + r1; t = t > 0.f ? t : SLOPE * t; p3 += t * at1;
        t = x32 + r2; t = t > 0.f ? t : SLOPE * t; p3 += t * at2;
        t = x33 + r3; t = t > 0.f ? t : SLOPE * t; p3 += t * at3;
        p0 += __shfl_xor(p0, 1); p1 += __shfl_xor(p1, 1); p2 += __shfl_xor(p2, 1); p3 += __shfl_xor(p3, 1);
        p0 += __shfl_xor(p0, 2); p1 += __shfl_xor(p1, 2); p2 += __shfl_xor(p2, 2); p3 += __shfl_xor(p3, 2);
        p0 += __shfl_xor(p0, 4); p1 += __shfl_xor(p1, 4); p2 += __shfl_xor(p2, 4); p3 += __shfl_xor(p3, 4);
        p0 += __shfl_xor(p0, 8); p1 += __shfl_xor(p1, 8); p2 += __shfl_xor(p2, 8); p3 += __shfl_xor(p3, 8);
        float pm = p0;
        if (v1) pm = fmaxf(pm, p1);
        if (v2) pm = fmaxf(pm, p2);
        if (v3) pm = fmaxf(pm, p3);
        float mn = fmaxf(m, pm);
        float sc = __expf(m - mn);
        float w0 = __expf(p0 - mn);
        float w1 = v1 ? __expf(p1 - mn) : 0.f;
        float w2 = v2 ? __expf(p2 - mn) : 0.f;
        float w3 = v3 ? __expf(p3 - mn) : 0.f;
        la = la * sc + w0 + w1 + w2 + w3;
        a0 = a0 * sc + w0 * x00 + w1 * x10 + w2 * x20 + w3 * x30;
        a1 = a1 * sc + w0 * x01 + w1 * x11 + w2 * x21 + w3 * x31;
        a2 = a2 * sc + w0 * x02 + w1 * x12 + w2 * x22 + w3 * x32;
        a3 = a3 * sc + w0 * x03 + w1 * x13 + w2 * x23 + w3 * x33;
        m = mn;
    }
    const float inv = 1.f / la;
    const int c = l * 4;
    float v0 = a0 * inv + bf2f(bias[c + 0]);
    float v1 = a1 * inv + bf2f(bias[c + 1]);
    float v2 = a2 * inv + bf2f(bias[c + 2]);
    float v3 = a3 * inv + bf2f(bias[c + 3]);
    v0 = v0 > 0.f ? v0 : __expf(fminf(v0, 0.f)) - 1.f;
    v1 = v1 > 0.f ? v1 : __expf(fminf(v1, 0.f)) - 1.f;
    v2 = v2 > 0.f ? v2 : __expf(fminf(v2, 0.f)) - 1.f;
    v3 = v3 > 0.f ? v3 : __expf(fminf(v3, 0.f)) - 1.f;
    ushort4 o;
    o.x = f2bf(v0); o.y = f2bf(v1); o.z = f2bf(v2); o.w = f2bf(v3);
    *(ushort4*)&hout[(size_t)d * C1 + c] = o;
}

// ---------------- layer 2 fused per-node GATv2 (1 head x 64 ch) --------------
// wave = 4x 16-lane groups, group g handles edge j+g. Edge indices loaded
// scalar (uniform) then selected per group; d scalarized via readfirstlane.
__global__ __launch_bounds__(256) void node2_kernel(
    const u16* __restrict__ xl, const u16* __restrict__ xr,
    const int* __restrict__ rowptr, const int* __restrict__ hist,
    const int* __restrict__ src_csr, const u16* __restrict__ att,
    const u16* __restrict__ bias, void* __restrict__ outp,
    const int* __restrict__ cnt)
{
    const int d = __builtin_amdgcn_readfirstlane(blockIdx.x * 4 + (threadIdx.x >> 6));
    if (d >= N_NODES) return;
    const int l = threadIdx.x & 63;
    const int start = rowptr[d];
    const int deg = hist[d];
    const int g = l >> 4, sub = l & 15;
    const int c0 = sub * 4;

    ushort4 av = *(const ushort4*)&att[c0];
    const float at0 = bf2f(av.x), at1 = bf2f(av.y), at2 = bf2f(av.z), at3 = bf2f(av.w);
    ushort4 rv = *(const ushort4*)&xr[(size_t)d * OUTC + c0];
    const float r0 = bf2f(rv.x), r1 = bf2f(rv.y), r2 = bf2f(rv.z), r3 = bf2f(rv.w);

    float m = -1e30f, la = 0.f;
    float a0 = 0.f, a1 = 0.f, a2 = 0.f, a3 = 0.f;
    for (int j = 0; j < deg; j += 4) {
        // scalar loads of up to 4 edge indices, then per-group select
        int s0 = src_csr[start + j];
        int s1 = (j + 1 < deg) ? src_csr[start + j + 1] : d;
        int s2 = (j + 2 < deg) ? src_csr[start + j + 2] : d;
        int s3 = (j + 3 < deg) ? src_csr[start + j + 3] : d;
        const bool valid = j + g < deg;
        int s = (g == 0) ? s0 : (g == 1) ? s1 : (g == 2) ? s2 : s3;
        ushort4 xv = *(const ushort4*)&xl[(size_t)s * OUTC + c0];
        float x0 = bf2f(xv.x), x1 = bf2f(xv.y), x2 = bf2f(xv.z), x3 = bf2f(xv.w);
        float t, p = 0.f;
        t = x0 + r0; t = t > 0.f ? t : SLOPE * t; p += t * at0;
        t = x1 + r1; t = t > 0.f ? t : SLOPE * t; p += t * at1;
        t = x2 + r2; t = t > 0.f ? t : SLOPE * t; p += t * at2;
        t = x3 + r3; t = t > 0.f ? t : SLOPE * t; p += t * at3;
        p += __shfl_xor(p, 1);   // group-local: xor of bits 0..3 stays in group
        p += __shfl_xor(p, 2);
        p += __shfl_xor(p, 4);
        p += __shfl_xor(p, 8);
        float pv = valid ? p : -1e30f;
        float mn = fmaxf(m, pv);
        float sc = __expf(m - mn);
        float w  = valid ? __expf(p - mn) : 0.f;
        la = la * sc + w;
        a0 = a0 * sc + w * x0;
        a1 = a1 * sc + w * x1;
        a2 = a2 * sc + w * x2;
        a3 = a3 * sc + w * x3;
        m = mn;
    }
    // merge the 4 groups' online-softmax states (xor 16, then 32)
    #pragma unroll
    for (int ofs = 16; ofs <= 32; ofs <<= 1) {
        float mo = __shfl_xor(m, ofs);
        float lo = __shfl_xor(la, ofs);
        float b0 = __shfl_xor(a0, ofs);
        float b1 = __shfl_xor(a1, ofs);
        float b2 = __shfl_xor(a2, ofs);
        float b3 = __shfl_xor(a3, ofs);
        float mn = fmaxf(m, mo);
        float s0 = __expf(m - mn), s1 = __expf(mo - mn);
        la = la * s0 + lo * s1;
        a0 = a0 * s0 + b0 * s1;
        a1 = a1 * s0 + b1 * s1;
        a2 = a2 * s0 + b2 * s1;
        a3 = a3 * s0 + b3 * s1;
        m = mn;
    }
    if (g == 0) {
        const float inv = 1.f / la;
        float v0 = a0 * inv + bf2f(bias[c0 + 0]);
        float v1 = a1 * inv + bf2f(bias[c0 + 1]);
        float v2 = a2 * inv + bf2f(bias[c0 + 2]);
        float v3 = a3 * inv + bf2f(bias[c0 + 3]);
        if (*cnt >= 32) {
            float4 o = make_float4(v0, v1, v2, v3);
            *(float4*)&((float*)outp)[(size_t)d * OUTC + c0] = o;
        } else {
            ushort4 o;
            o.x = f2bf(v0); o.y = f2bf(v1); o.z = f2bf(v2); o.w = f2bf(v3);
            *(ushort4*)&((u16*)outp)[(size_t)d * OUTC + c0] = o;
        }
    }
}

extern "C" void kernel_launch(void* const* d_in, const int* in_sizes, int n_in,
                              void* d_out, int out_size, void* d_ws, size_t ws_size,
                              hipStream_t stream)
{
    const void* x  = d_in[0];
    const int*  ei = (const int*)d_in[1];

    char* ws = (char*)d_ws;
    u16* xl1     = (u16*)(ws + 0);          // 25.6 MB
    u16* xr1     = (u16*)(ws + 25600000);   // 25.6 MB
    u16* hbuf    = (u16*)(ws + 51200000);   // 25.6 MB
    u16* xl2     = (u16*)(ws + 0);          // overlay xl1 (dead after node1)
    u16* xr2     = (u16*)(ws + 6400000);
    int* hist    = (int*)(ws + 76800000);
    int* rowptr  = (int*)(ws + 77000000);
    int* off     = (int*)(ws + 77200000);
    int* src_csr = (int*)(ws + 77400000);   // 1.8 MB
    int* cnt     = (int*)(ws + 79200000);
    u16* prm     = (u16*)(ws + 79200064);   // 1280 u16 small params
    u16* wt      = (u16*)(ws + 79210240);   // 98304 u16 transposed weights
    int* bsum    = (int*)(ws + 79410000);
    int* boff    = (int*)(ws + 79411024);

    u16* bl1   = prm + 0;
    u16* br1   = prm + 256;
    u16* att1  = prm + 512;
    u16* bias1 = prm + 768;
    u16* bl2   = prm + 1024;
    u16* br2   = prm + 1088;
    u16* att2  = prm + 1152;
    u16* bias2 = prm + 1216;
    u16* wt1   = wt + 0;       // [2][256][128]
    u16* wt2   = wt + 65536;   // [2][64][256]

    hipMemsetAsync(cnt, 0, 4, stream);
    detect_kernel<<<1, 256, 0, stream>>>((const unsigned*)x, cnt);
    convert_all_kernel<<<385, 256, 0, stream>>>(
        d_in[2], d_in[4], d_in[8], d_in[10],
        d_in[3], d_in[5], d_in[6], d_in[7], d_in[9], d_in[11], d_in[12], d_in[13],
        wt, prm, cnt);

    hipMemsetAsync(hist, 0, 200000, stream);
    const int eb = (ET + 255) / 256;
    hist_kernel<<<eb, 256, 0, stream>>>(ei, hist);
    scan1_kernel<<<196, 256, 0, stream>>>(hist, rowptr, bsum);
    scan2_kernel<<<1, 256, 0, stream>>>(bsum, boff);
    scan3_kernel<<<196, 256, 0, stream>>>(rowptr, boff, off);
    scatter_kernel<<<eb, 256, 0, stream>>>(ei, off, src_csr);

    const int gb = (N_NODES + 63) / 64;   // 782
    lin1_fused_kernel<<<gb, 256, 0, stream>>>((const u16*)x, wt1, bl1, br1, xl1, xr1, N_NODES, cnt);
    const int nb = (N_NODES * 64 + 255) / 256;   // 12500 blocks, 4 waves each
    node1_kernel<<<nb, 256, 0, stream>>>(xl1, xr1, rowptr, hist, src_csr, att1, bias1, hbuf);

    lin2_fused_kernel<<<gb, 256, 0, stream>>>(hbuf, wt2, bl2, br2, xl2, xr2, N_NODES);
    node2_kernel<<<nb, 256, 0, stream>>>(xl2, xr2, rowptr, hist, src_csr, att2, bias2, d_out, cnt);
}